// Round 5
// baseline (8006.354 us; speedup 1.0000x reference)
//
#include <hip/hip_runtime.h>
#include <hip/hip_bf16.h>

#define NN 6144
#define DD 64
#define NL 3
#define KK 24
#define RT 32   // rows per block (adj kernel)
#define CT 64   // cols per tile
#define KH 32   // k-half staged at a time
#define NT (NN / CT)
#define MB 4    // rows per block (mlp kernel)
#define KCLAMP 7.99881172180175781f

// Bit-level emulation of XLA CPU f32 tanh, FMA variant. Verified bit-exact
// vs reference (rounds 2-4, absmax 0.0).
__device__ __forceinline__ float tanh_xla(float x) {
  float xc = fminf(fmaxf(x, -KCLAMP), KCLAMP);
  float x2 = xc * xc;
  float p = -2.76076847742355e-16f;
  p = fmaf(p, x2, 2.00018790482477e-13f);
  p = fmaf(p, x2, -8.60467152213735e-11f);
  p = fmaf(p, x2, 5.12229709037114e-08f);
  p = fmaf(p, x2, 1.48572235717979e-05f);
  p = fmaf(p, x2, 6.37261928875436e-04f);
  p = fmaf(p, x2, 4.89352455891786e-03f);
  p = xc * p;
  float q = 1.19825839466702e-06f;
  q = fmaf(q, x2, 1.18534705686654e-04f);
  q = fmaf(q, x2, 2.26843463243900e-03f);
  q = fmaf(q, x2, 4.89352518554385e-03f);
  float r = p / q;
  return (fabsf(x) < 0.0004f) ? x : r;
}

// Kernel A: 3-layer tanh MLP chains, thread = (row, output j). Identical
// fmaf chain order to rounds 2-4 (bit-matches Eigen). Block = 4 rows x 64 j.
// Block 0 also computes Mtv = sampled global max of the rounded tanh rational
// over [7,8] (exact round-2 code, validated absmax 0.0).
__global__ __launch_bounds__(256) void mlp_kernel(
    const int* __restrict__ idx, const float* __restrict__ scale_set,
    const float* __restrict__ emb1, const float* __restrict__ emb2,
    const float* __restrict__ W1, const float* __restrict__ b1,
    const float* __restrict__ W2, const float* __restrict__ b2,
    float* __restrict__ vt1, float* __restrict__ vt2,
    float* __restrict__ mtv) {
  __shared__ float Wt1[DD][DD];                  // W[l][j][k] transposed -> [k][j]
  __shared__ float Wt2[DD][DD];
  __shared__ float bsh1[DD], bsh2[DD];
  __shared__ __align__(16) float o1sh[MB][DD];   // layer inputs/outputs
  __shared__ __align__(16) float o2sh[MB][DD];
  const int t = threadIdx.x;
  const int r = t >> 6;        // 0..3  (one wave per row)
  const int j = t & 63;        // 0..63 output index
  const int grow = blockIdx.x * MB + r;

  // Stage layer-0 inputs emb[idx[grow]] into o_sh.
  {
    int g = idx[grow];
    if (j < 16) {
      ((float4*)&o1sh[r][0])[j] = ((const float4*)(emb1 + (size_t)g * DD))[j];
      ((float4*)&o2sh[r][0])[j] = ((const float4*)(emb2 + (size_t)g * DD))[j];
    }
  }

  for (int l = 0; l < NL; ++l) {
    __syncthreads();   // (A) o_sh inputs ready; Wt free for overwrite
    // Stage transposed weights: Wt[k][j] = W[l][j][k] (conflict-free reads).
    {
      const float* w1p = W1 + ((size_t)l * DD + j) * DD + r * 16;
      const float* w2p = W2 + ((size_t)l * DD + j) * DD + r * 16;
#pragma unroll
      for (int w = 0; w < 4; ++w) {
        float4 a = *(const float4*)(w1p + 4 * w);
        float4 b = *(const float4*)(w2p + 4 * w);
        int k0 = r * 16 + 4 * w;
        Wt1[k0 + 0][j] = a.x; Wt1[k0 + 1][j] = a.y;
        Wt1[k0 + 2][j] = a.z; Wt1[k0 + 3][j] = a.w;
        Wt2[k0 + 0][j] = b.x; Wt2[k0 + 1][j] = b.y;
        Wt2[k0 + 2][j] = b.z; Wt2[k0 + 3][j] = b.w;
      }
    }
    if (t < DD) { bsh1[t] = b1[l * DD + t]; bsh2[t] = b2[l * DD + t]; }
    __syncthreads();   // (B) Wt, b ready

    const float s = scale_set[l];
    float a1 = 0.0f, a2 = 0.0f;
    // Ascending-k chain; u[k] = src[k]*s rounded separately, then fmaf.
#pragma unroll
    for (int kb = 0; kb < 16; ++kb) {
      float4 s1 = ((const float4*)&o1sh[r][0])[kb];
      float4 s2 = ((const float4*)&o2sh[r][0])[kb];
      int k0 = 4 * kb;
      a1 = fmaf(s1.x * s, Wt1[k0 + 0][j], a1);
      a1 = fmaf(s1.y * s, Wt1[k0 + 1][j], a1);
      a1 = fmaf(s1.z * s, Wt1[k0 + 2][j], a1);
      a1 = fmaf(s1.w * s, Wt1[k0 + 3][j], a1);
      a2 = fmaf(s2.x * s, Wt2[k0 + 0][j], a2);
      a2 = fmaf(s2.y * s, Wt2[k0 + 1][j], a2);
      a2 = fmaf(s2.z * s, Wt2[k0 + 2][j], a2);
      a2 = fmaf(s2.w * s, Wt2[k0 + 3][j], a2);
    }
    float t1 = tanh_xla(3.0f * (a1 + bsh1[j]));
    float t2 = tanh_xla(3.0f * (a2 + bsh2[j]));
    __syncthreads();   // (C) all reads of o_sh done
    o1sh[r][j] = t1;
    o2sh[r][j] = t2;
    vt1[((size_t)l * DD + j) * NN + grow] = t1;
    vt2[((size_t)l * DD + j) * NN + grow] = t2;
  }

  // Mtv: sampled max of the rounded rational on [7,8] (round-2 validated).
  if (blockIdx.x == 0) {
    __syncthreads();
    float lm = 0.0f;
    for (int i = 0; i < 96; ++i) {
      float x = 7.0f + (float)(t * 96 + i) * (1.0f / 24576.0f);
      lm = fmaxf(lm, tanh_xla(x));
    }
    ((float*)Wt1)[t] = lm;
    __syncthreads();
    if (t == 0) {
      float m = 0.0f;
      for (int i = 0; i < 256; ++i) m = fmaxf(m, ((float*)Wt1)[i]);
      mtv[0] = m;
    }
  }
}

// Kernel B: per (layer, 32-row tile). R staged full-k; C staged in k-halves
// with register prefetch (T14). Fused top-24 scan: athr prefilter + plateau
// fast-path + Mtv saturation freeze; ballot-serialized rare insertions.
__global__ __launch_bounds__(128) void adj_kernel(
    const float* __restrict__ vt1, const float* __restrict__ vt2,
    const float* __restrict__ mtv, float* __restrict__ out) {
  __shared__ float R1t[DD][RT];          // [k][row]   8KB
  __shared__ float R2t[DD][RT];          //            8KB
  __shared__ float C1h[KH][CT];          // [k'][col]  8KB (current k-half)
  __shared__ float C2h[KH][CT];          //            8KB
  __shared__ float kv[KK][RT];           // 3KB  topk values, slot 0 weakest
  __shared__ unsigned short ki[KK][RT];  // 1.5KB column indices
  __shared__ __align__(16) float athr[RT];  // 128B per-row reject threshold
  // LDS total ~36.6 KiB -> 4 blocks/CU (8 waves)

  const int l = blockIdx.y;
  const int r0 = blockIdx.x * RT;
  const int t = threadIdx.x;
  const int lane = t & 63;
  const float* w1 = vt1 + (size_t)l * DD * NN;   // k-major [k][col]
  const float* w2 = vt2 + (size_t)l * DD * NN;
  float* o = out + (size_t)l * NN * NN;
  const float Rclamp = tanh_xla(8.0f);  // exact plateau value (clamp)
  const float Mtv = mtv[0];

  // Zero-fill this block's 32-row output slab.
  {
    float4 z = make_float4(0.f, 0.f, 0.f, 0.f);
    float4* dst = (float4*)(o + (size_t)r0 * NN);
    for (int i = t; i < RT * NN / 4; i += 128) dst[i] = z;
  }

  // Stage R tiles (full k) from k-major vT.
#pragma unroll
  for (int kb = 0; kb < 4; ++kb) {
    int k = kb * 16 + (t >> 3);
    int c = (t & 7) * 4;
    *(float4*)&R1t[k][c] = *(const float4*)(w1 + (size_t)k * NN + r0 + c);
    *(float4*)&R2t[k][c] = *(const float4*)(w2 + (size_t)k * NN + r0 + c);
  }
  if (t < RT) {
    athr[t] = 0.0f;
#pragma unroll
    for (int q = 0; q < KK; ++q) { kv[q][t] = 0.0f; ki[q][t] = 0; }
  }

  const int ty = t >> 4;   // 0..7 -> 4 rows each
  const int tx = t & 15;   // 0..15 -> 4 cols each
  const int skk = t >> 4;  // staging k sub-index
  const int sc  = (t & 15) * 4;

  // Prefetch (ct=0, h=0).
  float4 pf1[4], pf2[4];
  {
    const size_t base = (size_t)0 * NN + sc;
#pragma unroll
    for (int m = 0; m < 4; ++m) {
      pf1[m] = *(const float4*)(w1 + base + (size_t)(m * 8 + skk) * NN);
      pf2[m] = *(const float4*)(w2 + base + (size_t)(m * 8 + skk) * NN);
    }
  }

  for (int ct = 0; ct < NT; ++ct) {
    float acc1[4][4] = {{0.f}}, acc2[4][4] = {{0.f}};
#pragma unroll
    for (int h = 0; h < 2; ++h) {
      __syncthreads();   // previous C contents fully consumed
      // Commit prefetched half to LDS.
#pragma unroll
      for (int m = 0; m < 4; ++m) {
        *(float4*)&C1h[m * 8 + skk][sc] = pf1[m];
        *(float4*)&C2h[m * 8 + skk][sc] = pf2[m];
      }
      __syncthreads();   // C ready
      // Prefetch next half (clamped to tile 0 at the very end; harmless).
      {
        int nct = (h == 0) ? ct : ((ct + 1 < NT) ? (ct + 1) : 0);
        int nh = h ^ 1;
        const size_t base = (size_t)(nh * KH) * NN + (size_t)nct * CT + sc;
#pragma unroll
        for (int m = 0; m < 4; ++m) {
          pf1[m] = *(const float4*)(w1 + base + (size_t)(m * 8 + skk) * NN);
          pf2[m] = *(const float4*)(w2 + base + (size_t)(m * 8 + skk) * NN);
        }
      }
      // Compute this k-half: sequential-k fmaf chains (bit-exact).
#pragma unroll 4
      for (int kk = 0; kk < KH; ++kk) {
        int k = h * KH + kk;
        float4 rv1 = *(const float4*)&R1t[k][4 * ty];
        float4 rv2 = *(const float4*)&R2t[k][4 * ty];
        float4 cv1 = *(const float4*)&C1h[kk][4 * tx];
        float4 cv2 = *(const float4*)&C2h[kk][4 * tx];
        const float* r1 = (const float*)&rv1;
        const float* r2 = (const float*)&rv2;
        const float* c1 = (const float*)&cv1;
        const float* c2 = (const float*)&cv2;
#pragma unroll
        for (int i = 0; i < 4; ++i)
#pragma unroll
          for (int jj = 0; jj < 4; ++jj) {
            acc1[i][jj] = fmaf(r1[i], c2[jj], acc1[i][jj]);  // v1_r . v2_c
            acc2[i][jj] = fmaf(r2[i], c1[jj], acc2[i][jj]);  // v2_r . v1_c
          }
      }
    }

    // Fused scan. Fast path: per-row athr prefilter (monotone, stale-safe;
    // frozen rows have athr=3e38).
    float xs[4][4];
    bool cand = false;
    {
      float4 at4 = *(const float4*)&athr[4 * ty];
      const float* a4 = (const float*)&at4;
#pragma unroll
      for (int i = 0; i < 4; ++i)
#pragma unroll
        for (int jj = 0; jj < 4; ++jj) {
          float x = 3.0f * (acc1[i][jj] - acc2[i][jj]);
          xs[i][jj] = x;
          cand |= (x > a4[i]);
        }
    }
    unsigned long long mball = __ballot(cand);
    if (mball) {
      // Ascending-lane order = ascending column order per row (rows are
      // wave-private; in-wave DS ordering serializes correctly).
      volatile float* kvv = &kv[0][0];
      volatile unsigned short* kiv = &ki[0][0];
      volatile float* atv = athr;
      const int c0t = ct * CT;
      do {
        int ln = __ffsll((unsigned long long)mball) - 1;
        if (ln == lane) {
#pragma unroll
          for (int i = 0; i < 4; ++i) {
            const int row = 4 * ty + i;
            for (int jj = 0; jj < 4; ++jj) {
              float x = xs[i][jj];
              if (x > atv[row]) {
                float tv = (x >= KCLAMP) ? Rclamp : tanh_xla(x);
                if (tv > kvv[row]) {
                  int pp = 1;
                  while (pp < KK && kvv[pp * RT + row] < tv) {
                    kvv[(pp - 1) * RT + row] = kvv[pp * RT + row];
                    kiv[(pp - 1) * RT + row] = kiv[pp * RT + row];
                    ++pp;
                  }
                  kvv[(pp - 1) * RT + row] = tv;
                  kiv[(pp - 1) * RT + row] = (unsigned short)(c0t + 4 * tx + jj);
                  float nv = kvv[row];
                  float ath;
                  if (nv >= Mtv) {
                    ath = 3.0e38f;   // saturation freeze (round-2 validated)
                  } else {
                    float y = nv - 2e-6f;
                    ath = (y > 0.0f)
                        ? (0.5f * logf((1.0f + y) / (1.0f - y)) - 4e-6f)
                        : 0.0f;
                  }
                  atv[row] = ath;
                }
              }
            }
          }
        }
        mball &= (mball - 1);
      } while (mball);
    }
  }
  __syncthreads();  // kv/ki final

  // Scatter top-24 nonzeros into the zeroed slab.
  if (t < RT) {
    float* orow = o + (size_t)(r0 + t) * NN;
#pragma unroll
    for (int q = 0; q < KK; ++q) {
      float v = kv[q][t];
      if (v > 0.0f) orow[ki[q][t]] = v;
    }
  }
}

extern "C" void kernel_launch(void* const* d_in, const int* in_sizes, int n_in,
                              void* d_out, int out_size, void* d_ws, size_t ws_size,
                              hipStream_t stream) {
  const int*   idx       = (const int*)d_in[0];
  const float* scale_set = (const float*)d_in[2];
  const float* emb1      = (const float*)d_in[3];
  const float* emb2      = (const float*)d_in[4];
  const float* W1        = (const float*)d_in[5];
  const float* b1        = (const float*)d_in[6];
  const float* W2        = (const float*)d_in[7];
  const float* b2        = (const float*)d_in[8];
  float* out = (float*)d_out;

  const size_t VS = (size_t)NL * NN * DD;
  float* vt1 = (float*)d_ws;      // k-major [3][64][6144]
  float* vt2 = vt1 + VS;
  float* mtv = vt2 + VS;          // [1]

  mlp_kernel<<<NN / MB, 256, 0, stream>>>(idx, scale_set, emb1, emb2, W1, b1, W2, b2,
                                          vt1, vt2, mtv);
  adj_kernel<<<dim3(NN / RT, NL), 128, 0, stream>>>(vt1, vt2, mtv, out);
}

// Round 6
// 1857.368 us; speedup vs baseline: 4.3106x; 4.3106x over previous
//
#include <hip/hip_runtime.h>
#include <hip/hip_bf16.h>

#define NN 6144
#define DD 64
#define NL 3
#define KK 24
#define RT 32   // rows per block (xmat kernel)
#define CT 64   // cols per tile
#define KH 32   // k-half staged at a time
#define NT (NN / CT)
#define MB 4    // rows per block (mlp kernel)
#define KCLAMP 7.99881172180175781f

// Bit-level emulation of XLA CPU f32 tanh, FMA variant. Verified bit-exact
// vs reference (rounds 2-5, absmax 0.0).
__device__ __forceinline__ float tanh_xla(float x) {
  float xc = fminf(fmaxf(x, -KCLAMP), KCLAMP);
  float x2 = xc * xc;
  float p = -2.76076847742355e-16f;
  p = fmaf(p, x2, 2.00018790482477e-13f);
  p = fmaf(p, x2, -8.60467152213735e-11f);
  p = fmaf(p, x2, 5.12229709037114e-08f);
  p = fmaf(p, x2, 1.48572235717979e-05f);
  p = fmaf(p, x2, 6.37261928875436e-04f);
  p = fmaf(p, x2, 4.89352455891786e-03f);
  p = xc * p;
  float q = 1.19825839466702e-06f;
  q = fmaf(q, x2, 1.18534705686654e-04f);
  q = fmaf(q, x2, 2.26843463243900e-03f);
  q = fmaf(q, x2, 4.89352518554385e-03f);
  float r = p / q;
  return (fabsf(x) < 0.0004f) ? x : r;
}

__device__ __forceinline__ unsigned long long shfl_xor_u64(unsigned long long v, int m) {
  unsigned lo = __shfl_xor((unsigned)v, m);
  unsigned hi = __shfl_xor((unsigned)(v >> 32), m);
  return ((unsigned long long)hi << 32) | lo;
}

// Kernel A: 3-layer tanh MLP chains, thread = (row, output j). Identical fmaf
// chain order to rounds 2-5 (bit-matches Eigen). Emits k-major vT only.
__global__ __launch_bounds__(256) void mlp_kernel(
    const int* __restrict__ idx, const float* __restrict__ scale_set,
    const float* __restrict__ emb1, const float* __restrict__ emb2,
    const float* __restrict__ W1, const float* __restrict__ b1,
    const float* __restrict__ W2, const float* __restrict__ b2,
    float* __restrict__ vt1, float* __restrict__ vt2) {
  __shared__ float Wt1[DD][DD];                  // W[l][j][k] -> [k][j]
  __shared__ float Wt2[DD][DD];
  __shared__ float bsh1[DD], bsh2[DD];
  __shared__ __align__(16) float o1sh[MB][DD];
  __shared__ __align__(16) float o2sh[MB][DD];
  const int t = threadIdx.x;
  const int r = t >> 6;
  const int j = t & 63;
  const int grow = blockIdx.x * MB + r;

  {
    int g = idx[grow];
    if (j < 16) {
      ((float4*)&o1sh[r][0])[j] = ((const float4*)(emb1 + (size_t)g * DD))[j];
      ((float4*)&o2sh[r][0])[j] = ((const float4*)(emb2 + (size_t)g * DD))[j];
    }
  }

  for (int l = 0; l < NL; ++l) {
    __syncthreads();
    {
      const float* w1p = W1 + ((size_t)l * DD + j) * DD + r * 16;
      const float* w2p = W2 + ((size_t)l * DD + j) * DD + r * 16;
#pragma unroll
      for (int w = 0; w < 4; ++w) {
        float4 a = *(const float4*)(w1p + 4 * w);
        float4 b = *(const float4*)(w2p + 4 * w);
        int k0 = r * 16 + 4 * w;
        Wt1[k0 + 0][j] = a.x; Wt1[k0 + 1][j] = a.y;
        Wt1[k0 + 2][j] = a.z; Wt1[k0 + 3][j] = a.w;
        Wt2[k0 + 0][j] = b.x; Wt2[k0 + 1][j] = b.y;
        Wt2[k0 + 2][j] = b.z; Wt2[k0 + 3][j] = b.w;
      }
    }
    if (t < DD) { bsh1[t] = b1[l * DD + t]; bsh2[t] = b2[l * DD + t]; }
    __syncthreads();

    const float s = scale_set[l];
    float a1 = 0.0f, a2 = 0.0f;
#pragma unroll
    for (int kb = 0; kb < 16; ++kb) {
      float4 s1 = ((const float4*)&o1sh[r][0])[kb];
      float4 s2 = ((const float4*)&o2sh[r][0])[kb];
      int k0 = 4 * kb;
      a1 = fmaf(s1.x * s, Wt1[k0 + 0][j], a1);
      a1 = fmaf(s1.y * s, Wt1[k0 + 1][j], a1);
      a1 = fmaf(s1.z * s, Wt1[k0 + 2][j], a1);
      a1 = fmaf(s1.w * s, Wt1[k0 + 3][j], a1);
      a2 = fmaf(s2.x * s, Wt2[k0 + 0][j], a2);
      a2 = fmaf(s2.y * s, Wt2[k0 + 1][j], a2);
      a2 = fmaf(s2.z * s, Wt2[k0 + 2][j], a2);
      a2 = fmaf(s2.w * s, Wt2[k0 + 3][j], a2);
    }
    float t1 = tanh_xla(3.0f * (a1 + bsh1[j]));
    float t2 = tanh_xla(3.0f * (a2 + bsh2[j]));
    __syncthreads();
    o1sh[r][j] = t1;
    o2sh[r][j] = t2;
    vt1[((size_t)l * DD + j) * NN + grow] = t1;
    vt2[((size_t)l * DD + j) * NN + grow] = t2;
  }
}

// Pass 1: pure tile GEMM. Computes x = 3*(v1_r.v2_c - v2_r.v1_c) via the
// validated sequential-k fmaf chains and stores ALL x values to out
// (used as scratch; replaces the zero-fill traffic). No top-k state.
__global__ __launch_bounds__(128) void xmat_kernel(
    const float* __restrict__ vt1, const float* __restrict__ vt2,
    float* __restrict__ out) {
  __shared__ float R1t[DD][RT];   // 8KB
  __shared__ float R2t[DD][RT];   // 8KB
  __shared__ float C1h[KH][CT];   // 8KB (current k-half)
  __shared__ float C2h[KH][CT];   // 8KB  -> 32KB total, 5 blocks/CU

  const int l = blockIdx.y;
  const int r0 = blockIdx.x * RT;
  const int t = threadIdx.x;
  const float* w1 = vt1 + (size_t)l * DD * NN;   // k-major [k][col]
  const float* w2 = vt2 + (size_t)l * DD * NN;
  float* o = out + (size_t)l * NN * NN;

  // Stage R tiles (full k).
#pragma unroll
  for (int kb = 0; kb < 4; ++kb) {
    int k = kb * 16 + (t >> 3);
    int c = (t & 7) * 4;
    *(float4*)&R1t[k][c] = *(const float4*)(w1 + (size_t)k * NN + r0 + c);
    *(float4*)&R2t[k][c] = *(const float4*)(w2 + (size_t)k * NN + r0 + c);
  }

  const int ty = t >> 4;   // 0..7 -> 4 rows each
  const int tx = t & 15;   // 0..15 -> 4 cols each
  const int skk = t >> 4;
  const int sc  = (t & 15) * 4;

  // Prefetch (ct=0, h=0).
  float4 pf1[4], pf2[4];
#pragma unroll
  for (int m = 0; m < 4; ++m) {
    pf1[m] = *(const float4*)(w1 + (size_t)(m * 8 + skk) * NN + sc);
    pf2[m] = *(const float4*)(w2 + (size_t)(m * 8 + skk) * NN + sc);
  }

  for (int ct = 0; ct < NT; ++ct) {
    float acc1[4][4] = {{0.f}}, acc2[4][4] = {{0.f}};
#pragma unroll
    for (int h = 0; h < 2; ++h) {
      __syncthreads();   // previous C contents consumed (iter 0: R ready)
#pragma unroll
      for (int m = 0; m < 4; ++m) {
        *(float4*)&C1h[m * 8 + skk][sc] = pf1[m];
        *(float4*)&C2h[m * 8 + skk][sc] = pf2[m];
      }
      __syncthreads();   // C ready
      // Prefetch next half (clamped at the very end; harmless).
      {
        int nct = (h == 0) ? ct : ((ct + 1 < NT) ? (ct + 1) : 0);
        int nh = h ^ 1;
        const size_t base = (size_t)(nh * KH) * NN + (size_t)nct * CT + sc;
#pragma unroll
        for (int m = 0; m < 4; ++m) {
          pf1[m] = *(const float4*)(w1 + base + (size_t)(m * 8 + skk) * NN);
          pf2[m] = *(const float4*)(w2 + base + (size_t)(m * 8 + skk) * NN);
        }
      }
      // Compute this k-half: sequential-k fmaf chains (bit-exact).
#pragma unroll 4
      for (int kk = 0; kk < KH; ++kk) {
        int k = h * KH + kk;
        float4 rv1 = *(const float4*)&R1t[k][4 * ty];
        float4 rv2 = *(const float4*)&R2t[k][4 * ty];
        float4 cv1 = *(const float4*)&C1h[kk][4 * tx];
        float4 cv2 = *(const float4*)&C2h[kk][4 * tx];
        const float* r1 = (const float*)&rv1;
        const float* r2 = (const float*)&rv2;
        const float* c1 = (const float*)&cv1;
        const float* c2 = (const float*)&cv2;
#pragma unroll
        for (int i = 0; i < 4; ++i)
#pragma unroll
          for (int jj = 0; jj < 4; ++jj) {
            acc1[i][jj] = fmaf(r1[i], c2[jj], acc1[i][jj]);  // v1_r . v2_c
            acc2[i][jj] = fmaf(r2[i], c1[jj], acc2[i][jj]);  // v2_r . v1_c
          }
      }
    }
    // Store x tile: coalesced float4 per row fragment.
    const int c0t = ct * CT;
#pragma unroll
    for (int i = 0; i < 4; ++i) {
      float4 xv;
      xv.x = 3.0f * (acc1[i][0] - acc2[i][0]);
      xv.y = 3.0f * (acc1[i][1] - acc2[i][1]);
      xv.z = 3.0f * (acc1[i][2] - acc2[i][2]);
      xv.w = 3.0f * (acc1[i][3] - acc2[i][3]);
      *(float4*)(o + (size_t)(r0 + 4 * ty + i) * NN + c0t + 4 * tx) = xv;
    }
  }
}

// Pass 2: one wave per row (4 waves/block, no __syncthreads). Per lane:
// 96 entries -> tanh on positives -> per-lane LDS top-24 (strict '>',
// ascending index). Merge: 24 butterfly-max rounds on key (vbits<<32)|
// (0xFFFF-idx) == (value desc, index asc). Zero + owner-lane scatter.
__global__ __launch_bounds__(256) void topk_kernel(float* __restrict__ out) {
  __shared__ float kvL[KK][256];          // 24KB  per-thread top list (own col)
  __shared__ unsigned short kiL[KK][256]; // 12KB
  const int t = threadIdx.x;
  const int w = t >> 6;
  const int lane = t & 63;
  const int row = blockIdx.x * 4 + w;     // 0..18431 (layer*NN + row)
  float* rp = out + (size_t)row * NN;

#pragma unroll
  for (int q = 0; q < KK; ++q) { kvL[q][t] = 0.0f; kiL[q][t] = 0; }
  float kv0 = 0.0f;

  // Scan: lane owns dwords (s*64+lane)*4 .. +3, ascending index order.
  for (int s = 0; s < 24; ++s) {
    float4 x4 = *(const float4*)(rp + (size_t)(s * 64 + lane) * 4);
    const float* xp = (const float*)&x4;
#pragma unroll
    for (int jj = 0; jj < 4; ++jj) {
      float x = xp[jj];
      if (x > 0.0f) {
        float tv = tanh_xla(x);
        if (tv > kv0) {
          int p = 1;
          while (p < KK && kvL[p][t] < tv) {
            kvL[p - 1][t] = kvL[p][t];
            kiL[p - 1][t] = kiL[p][t];
            ++p;
          }
          kvL[p - 1][t] = tv;
          kiL[p - 1][t] = (unsigned short)(s * 256 + lane * 4 + jj);
          kv0 = kvL[0][t];
        }
      }
    }
  }

  // Merge across the wave: 24 extraction rounds (results kept in registers
  // via full unroll; winner unique because indices are unique).
  float resv[KK];
  int resi[KK];
  int hp = KK - 1;
#pragma unroll
  for (int r = 0; r < KK; ++r) {
    float hv = (hp >= 0) ? kvL[hp][t] : 0.0f;
    unsigned hi_ = (hp >= 0) ? (unsigned)kiL[hp][t] : 0u;
    unsigned long long mykey =
        ((unsigned long long)__float_as_uint(hv) << 32) | (0xFFFFu - hi_);
    unsigned long long key = mykey;
#pragma unroll
    for (int d = 1; d < 64; d <<= 1) {
      unsigned long long o2 = shfl_xor_u64(key, d);
      key = (o2 > key) ? o2 : key;
    }
    resv[r] = __uint_as_float((unsigned)(key >> 32));
    resi[r] = (int)(0xFFFFu - (unsigned)(key & 0xFFFFFFFFull));
    if (mykey == key && hp >= 0) --hp;   // pop (zero-key dupes harmless)
  }

  // Zero the row (lane-owned float4s), then owner-lane scatter: same-thread
  // same-address ordering guarantees the scatter survives.
  float4 z = make_float4(0.f, 0.f, 0.f, 0.f);
  for (int s = 0; s < 24; ++s)
    *(float4*)(rp + (size_t)(s * 64 + lane) * 4) = z;
#pragma unroll
  for (int r = 0; r < KK; ++r) {
    float v = resv[r];
    int ix = resi[r];
    if (v > 0.0f && ((ix >> 2) & 63) == lane) rp[ix] = v;
  }
}

extern "C" void kernel_launch(void* const* d_in, const int* in_sizes, int n_in,
                              void* d_out, int out_size, void* d_ws, size_t ws_size,
                              hipStream_t stream) {
  const int*   idx       = (const int*)d_in[0];
  const float* scale_set = (const float*)d_in[2];
  const float* emb1      = (const float*)d_in[3];
  const float* emb2      = (const float*)d_in[4];
  const float* W1        = (const float*)d_in[5];
  const float* b1        = (const float*)d_in[6];
  const float* W2        = (const float*)d_in[7];
  const float* b2        = (const float*)d_in[8];
  float* out = (float*)d_out;

  const size_t VS = (size_t)NL * NN * DD;
  float* vt1 = (float*)d_ws;      // k-major [3][64][6144]
  float* vt2 = vt1 + VS;

  mlp_kernel<<<NN / MB, 256, 0, stream>>>(idx, scale_set, emb1, emb2, W1, b1, W2, b2,
                                          vt1, vt2);
  xmat_kernel<<<dim3(NN / RT, NL), 128, 0, stream>>>(vt1, vt2, out);
  topk_kernel<<<(NL * NN) / 4, 256, 0, stream>>>(out);
}

// Round 7
// 1164.062 us; speedup vs baseline: 6.8779x; 1.5956x over previous
//
#include <hip/hip_runtime.h>
#include <hip/hip_bf16.h>

#define NN 6144
#define DD 64
#define NL 3
#define KK 24
#define BT 64   // pair-tile dimension (xmat kernel)
#define KH 32   // k-half staged at a time
#define MB 4    // rows per block (mlp kernel)
#define KCLAMP 7.99881172180175781f

// Bit-level emulation of XLA CPU f32 tanh, FMA variant. Verified bit-exact
// vs reference (rounds 2-6, absmax 0.0).
__device__ __forceinline__ float tanh_xla(float x) {
  float xc = fminf(fmaxf(x, -KCLAMP), KCLAMP);
  float x2 = xc * xc;
  float p = -2.76076847742355e-16f;
  p = fmaf(p, x2, 2.00018790482477e-13f);
  p = fmaf(p, x2, -8.60467152213735e-11f);
  p = fmaf(p, x2, 5.12229709037114e-08f);
  p = fmaf(p, x2, 1.48572235717979e-05f);
  p = fmaf(p, x2, 6.37261928875436e-04f);
  p = fmaf(p, x2, 4.89352455891786e-03f);
  p = xc * p;
  float q = 1.19825839466702e-06f;
  q = fmaf(q, x2, 1.18534705686654e-04f);
  q = fmaf(q, x2, 2.26843463243900e-03f);
  q = fmaf(q, x2, 4.89352518554385e-03f);
  float r = p / q;
  return (fabsf(x) < 0.0004f) ? x : r;
}

__device__ __forceinline__ unsigned long long shfl_xor_u64(unsigned long long v, int m) {
  unsigned lo = __shfl_xor((unsigned)v, m);
  unsigned hi = __shfl_xor((unsigned)(v >> 32), m);
  return ((unsigned long long)hi << 32) | lo;
}

// Kernel A: 3-layer tanh MLP chains, thread = (row, output j). Identical fmaf
// chain order to rounds 2-6 (bit-matches Eigen). Emits k-major vT only.
__global__ __launch_bounds__(256) void mlp_kernel(
    const int* __restrict__ idx, const float* __restrict__ scale_set,
    const float* __restrict__ emb1, const float* __restrict__ emb2,
    const float* __restrict__ W1, const float* __restrict__ b1,
    const float* __restrict__ W2, const float* __restrict__ b2,
    float* __restrict__ vt1, float* __restrict__ vt2) {
  __shared__ float Wt1[DD][DD];                  // W[l][j][k] -> [k][j]
  __shared__ float Wt2[DD][DD];
  __shared__ float bsh1[DD], bsh2[DD];
  __shared__ __align__(16) float o1sh[MB][DD];
  __shared__ __align__(16) float o2sh[MB][DD];
  const int t = threadIdx.x;
  const int r = t >> 6;
  const int j = t & 63;
  const int grow = blockIdx.x * MB + r;

  {
    int g = idx[grow];
    if (j < 16) {
      ((float4*)&o1sh[r][0])[j] = ((const float4*)(emb1 + (size_t)g * DD))[j];
      ((float4*)&o2sh[r][0])[j] = ((const float4*)(emb2 + (size_t)g * DD))[j];
    }
  }

  for (int l = 0; l < NL; ++l) {
    __syncthreads();
    {
      const float* w1p = W1 + ((size_t)l * DD + j) * DD + r * 16;
      const float* w2p = W2 + ((size_t)l * DD + j) * DD + r * 16;
#pragma unroll
      for (int w = 0; w < 4; ++w) {
        float4 a = *(const float4*)(w1p + 4 * w);
        float4 b = *(const float4*)(w2p + 4 * w);
        int k0 = r * 16 + 4 * w;
        Wt1[k0 + 0][j] = a.x; Wt1[k0 + 1][j] = a.y;
        Wt1[k0 + 2][j] = a.z; Wt1[k0 + 3][j] = a.w;
        Wt2[k0 + 0][j] = b.x; Wt2[k0 + 1][j] = b.y;
        Wt2[k0 + 2][j] = b.z; Wt2[k0 + 3][j] = b.w;
      }
    }
    if (t < DD) { bsh1[t] = b1[l * DD + t]; bsh2[t] = b2[l * DD + t]; }
    __syncthreads();

    const float s = scale_set[l];
    float a1 = 0.0f, a2 = 0.0f;
#pragma unroll
    for (int kb = 0; kb < 16; ++kb) {
      float4 s1 = ((const float4*)&o1sh[r][0])[kb];
      float4 s2 = ((const float4*)&o2sh[r][0])[kb];
      int k0 = 4 * kb;
      a1 = fmaf(s1.x * s, Wt1[k0 + 0][j], a1);
      a1 = fmaf(s1.y * s, Wt1[k0 + 1][j], a1);
      a1 = fmaf(s1.z * s, Wt1[k0 + 2][j], a1);
      a1 = fmaf(s1.w * s, Wt1[k0 + 3][j], a1);
      a2 = fmaf(s2.x * s, Wt2[k0 + 0][j], a2);
      a2 = fmaf(s2.y * s, Wt2[k0 + 1][j], a2);
      a2 = fmaf(s2.z * s, Wt2[k0 + 2][j], a2);
      a2 = fmaf(s2.w * s, Wt2[k0 + 3][j], a2);
    }
    float t1 = tanh_xla(3.0f * (a1 + bsh1[j]));
    float t2 = tanh_xla(3.0f * (a2 + bsh2[j]));
    __syncthreads();
    o1sh[r][j] = t1;
    o2sh[r][j] = t2;
    vt1[((size_t)l * DD + j) * NN + grow] = t1;
    vt2[((size_t)l * DD + j) * NN + grow] = t2;
  }
}

// Pass 1: antisymmetric pair-tile GEMM. Block (a,b,l) with a<=b computes the
// 64x64 tile x[r0..][c0..] via the validated sequential-k fmaf chains and
// stores it AND its mirrored tile. Mirror is bit-exact: ref's chains for
// (c,r) are fmaf(v1[c][k], v2[r][k]) == our acc2 chain (IEEE mul commutes),
// so x[c][r] = 3*(acc2 - acc1) bitwise. Diagonal blocks store direct only.
__global__ __launch_bounds__(128) void xmat_kernel(
    const float* __restrict__ vt1, const float* __restrict__ vt2,
    float* __restrict__ out) {
  __shared__ float R1h[KH][BT];   // [k'][row] 8KB
  __shared__ float R2h[KH][BT];   // 8KB
  __shared__ float C1h[KH][BT];   // [k'][col] 8KB
  __shared__ float C2h[KH][BT];   // 8KB  -> 32KB total, 5 blocks/CU

  const int a = blockIdx.x;
  const int b = blockIdx.y;
  if (b < a) return;              // upper triangle only (uniform exit)
  const int l = blockIdx.z;
  const int t = threadIdx.x;
  const int r0 = a * BT;
  const int c0 = b * BT;
  const float* w1 = vt1 + (size_t)l * DD * NN;   // k-major [k][col]
  const float* w2 = vt2 + (size_t)l * DD * NN;
  float* o = out + (size_t)l * NN * NN;

  const int ty = t >> 3;    // 0..15 -> 4 rows each
  const int tx = t & 7;     // 0..7  -> 8 cols each
  const int stk = t >> 4;   // staging k sub-index 0..7
  const int stc = (t & 15) * 4;

  float acc1[4][8] = {{0.f}}, acc2[4][8] = {{0.f}};

#pragma unroll
  for (int h = 0; h < 2; ++h) {
    __syncthreads();   // h=0: nothing pending; h=1: previous half consumed
    // Stage this k-half of both sides (coalesced float4 from L2-resident vT).
#pragma unroll
    for (int m = 0; m < 4; ++m) {
      int k = m * 8 + stk;
      const size_t src = (size_t)(h * KH + k) * NN;
      *(float4*)&R1h[k][stc] = *(const float4*)(w1 + src + r0 + stc);
      *(float4*)&R2h[k][stc] = *(const float4*)(w2 + src + r0 + stc);
      *(float4*)&C1h[k][stc] = *(const float4*)(w1 + src + c0 + stc);
      *(float4*)&C2h[k][stc] = *(const float4*)(w2 + src + c0 + stc);
    }
    __syncthreads();
    // Compute this k-half: sequential-k fmaf chains (bit-exact).
#pragma unroll 4
    for (int kk = 0; kk < KH; ++kk) {
      float4 rv1 = *(const float4*)&R1h[kk][4 * ty];
      float4 rv2 = *(const float4*)&R2h[kk][4 * ty];
      float4 cv1a = *(const float4*)&C1h[kk][8 * tx];
      float4 cv1b = *(const float4*)&C1h[kk][8 * tx + 4];
      float4 cv2a = *(const float4*)&C2h[kk][8 * tx];
      float4 cv2b = *(const float4*)&C2h[kk][8 * tx + 4];
      const float* r1 = (const float*)&rv1;
      const float* r2 = (const float*)&rv2;
      float c1[8], c2[8];
      *(float4*)&c1[0] = cv1a; *(float4*)&c1[4] = cv1b;
      *(float4*)&c2[0] = cv2a; *(float4*)&c2[4] = cv2b;
#pragma unroll
      for (int i = 0; i < 4; ++i)
#pragma unroll
        for (int j = 0; j < 8; ++j) {
          acc1[i][j] = fmaf(r1[i], c2[j], acc1[i][j]);  // v1_r . v2_c
          acc2[i][j] = fmaf(r2[i], c1[j], acc2[i][j]);  // v2_r . v1_c
        }
    }
  }

  // Direct tile store.
#pragma unroll
  for (int i = 0; i < 4; ++i) {
    float4 xa, xb;
    xa.x = 3.0f * (acc1[i][0] - acc2[i][0]);
    xa.y = 3.0f * (acc1[i][1] - acc2[i][1]);
    xa.z = 3.0f * (acc1[i][2] - acc2[i][2]);
    xa.w = 3.0f * (acc1[i][3] - acc2[i][3]);
    xb.x = 3.0f * (acc1[i][4] - acc2[i][4]);
    xb.y = 3.0f * (acc1[i][5] - acc2[i][5]);
    xb.z = 3.0f * (acc1[i][6] - acc2[i][6]);
    xb.w = 3.0f * (acc1[i][7] - acc2[i][7]);
    float* p = o + (size_t)(r0 + 4 * ty + i) * NN + c0 + 8 * tx;
    *(float4*)p = xa;
    *(float4*)(p + 4) = xb;
  }
  // Mirrored tile store (bit-exact antisymmetric counterpart).
  if (b > a) {
#pragma unroll
    for (int j = 0; j < 8; ++j) {
      float4 xt;
      xt.x = 3.0f * (acc2[0][j] - acc1[0][j]);
      xt.y = 3.0f * (acc2[1][j] - acc1[1][j]);
      xt.z = 3.0f * (acc2[2][j] - acc1[2][j]);
      xt.w = 3.0f * (acc2[3][j] - acc1[3][j]);
      *(float4*)(o + (size_t)(c0 + 8 * tx + j) * NN + r0 + 4 * ty) = xt;
    }
  }
}

// Pass 2: one wave per row (4 waves/block, no __syncthreads). Per lane:
// 96 entries -> tanh on positives -> per-lane LDS top-24 (strict '>',
// ascending index). Merge: 24 butterfly-max rounds on key (vbits<<32)|
// (0xFFFF-idx) == (value desc, index asc). Zero + owner-lane scatter.
__global__ __launch_bounds__(256) void topk_kernel(float* __restrict__ out) {
  __shared__ float kvL[KK][256];          // 24KB  per-thread top list (own col)
  __shared__ unsigned short kiL[KK][256]; // 12KB
  const int t = threadIdx.x;
  const int w = t >> 6;
  const int lane = t & 63;
  const int row = blockIdx.x * 4 + w;     // 0..18431 (layer*NN + row)
  float* rp = out + (size_t)row * NN;

#pragma unroll
  for (int q = 0; q < KK; ++q) { kvL[q][t] = 0.0f; kiL[q][t] = 0; }
  float kv0 = 0.0f;

  // Scan: lane owns dwords (s*64+lane)*4 .. +3, ascending index order.
  for (int s = 0; s < 24; ++s) {
    float4 x4 = *(const float4*)(rp + (size_t)(s * 64 + lane) * 4);
    const float* xp = (const float*)&x4;
#pragma unroll
    for (int jj = 0; jj < 4; ++jj) {
      float x = xp[jj];
      if (x > 0.0f) {
        float tv = tanh_xla(x);
        if (tv > kv0) {
          int p = 1;
          while (p < KK && kvL[p][t] < tv) {
            kvL[p - 1][t] = kvL[p][t];
            kiL[p - 1][t] = kiL[p][t];
            ++p;
          }
          kvL[p - 1][t] = tv;
          kiL[p - 1][t] = (unsigned short)(s * 256 + lane * 4 + jj);
          kv0 = kvL[0][t];
        }
      }
    }
  }

  // Merge across the wave: 24 extraction rounds (results kept in registers
  // via full unroll; winner unique because indices are unique).
  float resv[KK];
  int resi[KK];
  int hp = KK - 1;
#pragma unroll
  for (int r = 0; r < KK; ++r) {
    float hv = (hp >= 0) ? kvL[hp][t] : 0.0f;
    unsigned hi_ = (hp >= 0) ? (unsigned)kiL[hp][t] : 0u;
    unsigned long long mykey =
        ((unsigned long long)__float_as_uint(hv) << 32) | (0xFFFFu - hi_);
    unsigned long long key = mykey;
#pragma unroll
    for (int d = 1; d < 64; d <<= 1) {
      unsigned long long o2 = shfl_xor_u64(key, d);
      key = (o2 > key) ? o2 : key;
    }
    resv[r] = __uint_as_float((unsigned)(key >> 32));
    resi[r] = (int)(0xFFFFu - (unsigned)(key & 0xFFFFFFFFull));
    if (mykey == key && hp >= 0) --hp;   // pop (zero-key dupes harmless)
  }

  // Zero the row (lane-owned float4s), then owner-lane scatter: same-thread
  // same-address ordering guarantees the scatter survives.
  float4 z = make_float4(0.f, 0.f, 0.f, 0.f);
  for (int s = 0; s < 24; ++s)
    *(float4*)(rp + (size_t)(s * 64 + lane) * 4) = z;
#pragma unroll
  for (int r = 0; r < KK; ++r) {
    float v = resv[r];
    int ix = resi[r];
    if (v > 0.0f && ((ix >> 2) & 63) == lane) rp[ix] = v;
  }
}

extern "C" void kernel_launch(void* const* d_in, const int* in_sizes, int n_in,
                              void* d_out, int out_size, void* d_ws, size_t ws_size,
                              hipStream_t stream) {
  const int*   idx       = (const int*)d_in[0];
  const float* scale_set = (const float*)d_in[2];
  const float* emb1      = (const float*)d_in[3];
  const float* emb2      = (const float*)d_in[4];
  const float* W1        = (const float*)d_in[5];
  const float* b1        = (const float*)d_in[6];
  const float* W2        = (const float*)d_in[7];
  const float* b2        = (const float*)d_in[8];
  float* out = (float*)d_out;

  const size_t VS = (size_t)NL * NN * DD;
  float* vt1 = (float*)d_ws;      // k-major [3][64][6144]
  float* vt2 = vt1 + VS;

  mlp_kernel<<<NN / MB, 256, 0, stream>>>(idx, scale_set, emb1, emb2, W1, b1, W2, b2,
                                          vt1, vt2);
  xmat_kernel<<<dim3(NN / BT, NN / BT, NL), 128, 0, stream>>>(vt1, vt2, out);
  topk_kernel<<<(NL * NN) / 4, 256, 0, stream>>>(out);
}

// Round 8
// 833.441 us; speedup vs baseline: 9.6064x; 1.3967x over previous
//
#include <hip/hip_runtime.h>
#include <hip/hip_bf16.h>

#define NN 6144
#define DD 64
#define NL 3
#define KK 24
#define BT 64   // pair-tile dimension (xmat kernel)
#define KH 32   // k-half staged at a time
#define MB 4    // rows per block (mlp kernel)
#define KCLAMP 7.99881172180175781f

// Bit-level emulation of XLA CPU f32 tanh, FMA variant. Verified bit-exact
// vs reference (rounds 2-7, absmax 0.0).
__device__ __forceinline__ float tanh_xla(float x) {
  float xc = fminf(fmaxf(x, -KCLAMP), KCLAMP);
  float x2 = xc * xc;
  float p = -2.76076847742355e-16f;
  p = fmaf(p, x2, 2.00018790482477e-13f);
  p = fmaf(p, x2, -8.60467152213735e-11f);
  p = fmaf(p, x2, 5.12229709037114e-08f);
  p = fmaf(p, x2, 1.48572235717979e-05f);
  p = fmaf(p, x2, 6.37261928875436e-04f);
  p = fmaf(p, x2, 4.89352455891786e-03f);
  p = xc * p;
  float q = 1.19825839466702e-06f;
  q = fmaf(q, x2, 1.18534705686654e-04f);
  q = fmaf(q, x2, 2.26843463243900e-03f);
  q = fmaf(q, x2, 4.89352518554385e-03f);
  float r = p / q;
  return (fabsf(x) < 0.0004f) ? x : r;
}

__device__ __forceinline__ unsigned long long shfl_xor_u64(unsigned long long v, int m) {
  unsigned lo = __shfl_xor((unsigned)v, m);
  unsigned hi = __shfl_xor((unsigned)(v >> 32), m);
  return ((unsigned long long)hi << 32) | lo;
}

// Kernel A: 3-layer tanh MLP chains, thread = (row, output j). Identical fmaf
// chain order to rounds 2-7 (bit-matches Eigen). Emits k-major vT only.
__global__ __launch_bounds__(256) void mlp_kernel(
    const int* __restrict__ idx, const float* __restrict__ scale_set,
    const float* __restrict__ emb1, const float* __restrict__ emb2,
    const float* __restrict__ W1, const float* __restrict__ b1,
    const float* __restrict__ W2, const float* __restrict__ b2,
    float* __restrict__ vt1, float* __restrict__ vt2) {
  __shared__ float Wt1[DD][DD];                  // W[l][j][k] -> [k][j]
  __shared__ float Wt2[DD][DD];
  __shared__ float bsh1[DD], bsh2[DD];
  __shared__ __align__(16) float o1sh[MB][DD];
  __shared__ __align__(16) float o2sh[MB][DD];
  const int t = threadIdx.x;
  const int r = t >> 6;
  const int j = t & 63;
  const int grow = blockIdx.x * MB + r;

  {
    int g = idx[grow];
    if (j < 16) {
      ((float4*)&o1sh[r][0])[j] = ((const float4*)(emb1 + (size_t)g * DD))[j];
      ((float4*)&o2sh[r][0])[j] = ((const float4*)(emb2 + (size_t)g * DD))[j];
    }
  }

  for (int l = 0; l < NL; ++l) {
    __syncthreads();
    {
      const float* w1p = W1 + ((size_t)l * DD + j) * DD + r * 16;
      const float* w2p = W2 + ((size_t)l * DD + j) * DD + r * 16;
#pragma unroll
      for (int w = 0; w < 4; ++w) {
        float4 a = *(const float4*)(w1p + 4 * w);
        float4 b = *(const float4*)(w2p + 4 * w);
        int k0 = r * 16 + 4 * w;
        Wt1[k0 + 0][j] = a.x; Wt1[k0 + 1][j] = a.y;
        Wt1[k0 + 2][j] = a.z; Wt1[k0 + 3][j] = a.w;
        Wt2[k0 + 0][j] = b.x; Wt2[k0 + 1][j] = b.y;
        Wt2[k0 + 2][j] = b.z; Wt2[k0 + 3][j] = b.w;
      }
    }
    if (t < DD) { bsh1[t] = b1[l * DD + t]; bsh2[t] = b2[l * DD + t]; }
    __syncthreads();

    const float s = scale_set[l];
    float a1 = 0.0f, a2 = 0.0f;
#pragma unroll
    for (int kb = 0; kb < 16; ++kb) {
      float4 s1 = ((const float4*)&o1sh[r][0])[kb];
      float4 s2 = ((const float4*)&o2sh[r][0])[kb];
      int k0 = 4 * kb;
      a1 = fmaf(s1.x * s, Wt1[k0 + 0][j], a1);
      a1 = fmaf(s1.y * s, Wt1[k0 + 1][j], a1);
      a1 = fmaf(s1.z * s, Wt1[k0 + 2][j], a1);
      a1 = fmaf(s1.w * s, Wt1[k0 + 3][j], a1);
      a2 = fmaf(s2.x * s, Wt2[k0 + 0][j], a2);
      a2 = fmaf(s2.y * s, Wt2[k0 + 1][j], a2);
      a2 = fmaf(s2.z * s, Wt2[k0 + 2][j], a2);
      a2 = fmaf(s2.w * s, Wt2[k0 + 3][j], a2);
    }
    float t1 = tanh_xla(3.0f * (a1 + bsh1[j]));
    float t2 = tanh_xla(3.0f * (a2 + bsh2[j]));
    __syncthreads();
    o1sh[r][j] = t1;
    o2sh[r][j] = t2;
    vt1[((size_t)l * DD + j) * NN + grow] = t1;
    vt2[((size_t)l * DD + j) * NN + grow] = t2;
  }
}

// Pass 1: antisymmetric pair-tile GEMM. Block (a,b,l) with a<=b computes the
// 64x64 tile x[r0..][c0..] via the validated sequential-k fmaf chains and
// stores it AND its bit-exact mirrored tile (IEEE mul commutes; see round 7).
__global__ __launch_bounds__(128) void xmat_kernel(
    const float* __restrict__ vt1, const float* __restrict__ vt2,
    float* __restrict__ out) {
  __shared__ float R1h[KH][BT];   // [k'][row] 8KB
  __shared__ float R2h[KH][BT];   // 8KB
  __shared__ float C1h[KH][BT];   // [k'][col] 8KB
  __shared__ float C2h[KH][BT];   // 8KB  -> 32KB total, 5 blocks/CU

  const int a = blockIdx.x;
  const int b = blockIdx.y;
  if (b < a) return;              // upper triangle only (uniform exit)
  const int l = blockIdx.z;
  const int t = threadIdx.x;
  const int r0 = a * BT;
  const int c0 = b * BT;
  const float* w1 = vt1 + (size_t)l * DD * NN;   // k-major [k][col]
  const float* w2 = vt2 + (size_t)l * DD * NN;
  float* o = out + (size_t)l * NN * NN;

  const int ty = t >> 3;    // 0..15 -> 4 rows each
  const int tx = t & 7;     // 0..7  -> 8 cols each
  const int stk = t >> 4;   // staging k sub-index 0..7
  const int stc = (t & 15) * 4;

  float acc1[4][8] = {{0.f}}, acc2[4][8] = {{0.f}};

#pragma unroll
  for (int h = 0; h < 2; ++h) {
    __syncthreads();
#pragma unroll
    for (int m = 0; m < 4; ++m) {
      int k = m * 8 + stk;
      const size_t src = (size_t)(h * KH + k) * NN;
      *(float4*)&R1h[k][stc] = *(const float4*)(w1 + src + r0 + stc);
      *(float4*)&R2h[k][stc] = *(const float4*)(w2 + src + r0 + stc);
      *(float4*)&C1h[k][stc] = *(const float4*)(w1 + src + c0 + stc);
      *(float4*)&C2h[k][stc] = *(const float4*)(w2 + src + c0 + stc);
    }
    __syncthreads();
#pragma unroll 4
    for (int kk = 0; kk < KH; ++kk) {
      float4 rv1 = *(const float4*)&R1h[kk][4 * ty];
      float4 rv2 = *(const float4*)&R2h[kk][4 * ty];
      float4 cv1a = *(const float4*)&C1h[kk][8 * tx];
      float4 cv1b = *(const float4*)&C1h[kk][8 * tx + 4];
      float4 cv2a = *(const float4*)&C2h[kk][8 * tx];
      float4 cv2b = *(const float4*)&C2h[kk][8 * tx + 4];
      const float* r1 = (const float*)&rv1;
      const float* r2 = (const float*)&rv2;
      float c1[8], c2[8];
      *(float4*)&c1[0] = cv1a; *(float4*)&c1[4] = cv1b;
      *(float4*)&c2[0] = cv2a; *(float4*)&c2[4] = cv2b;
#pragma unroll
      for (int i = 0; i < 4; ++i)
#pragma unroll
        for (int j = 0; j < 8; ++j) {
          acc1[i][j] = fmaf(r1[i], c2[j], acc1[i][j]);  // v1_r . v2_c
          acc2[i][j] = fmaf(r2[i], c1[j], acc2[i][j]);  // v2_r . v1_c
        }
    }
  }

#pragma unroll
  for (int i = 0; i < 4; ++i) {
    float4 xa, xb;
    xa.x = 3.0f * (acc1[i][0] - acc2[i][0]);
    xa.y = 3.0f * (acc1[i][1] - acc2[i][1]);
    xa.z = 3.0f * (acc1[i][2] - acc2[i][2]);
    xa.w = 3.0f * (acc1[i][3] - acc2[i][3]);
    xb.x = 3.0f * (acc1[i][4] - acc2[i][4]);
    xb.y = 3.0f * (acc1[i][5] - acc2[i][5]);
    xb.z = 3.0f * (acc1[i][6] - acc2[i][6]);
    xb.w = 3.0f * (acc1[i][7] - acc2[i][7]);
    float* p = o + (size_t)(r0 + 4 * ty + i) * NN + c0 + 8 * tx;
    *(float4*)p = xa;
    *(float4*)(p + 4) = xb;
  }
  if (b > a) {
#pragma unroll
    for (int j = 0; j < 8; ++j) {
      float4 xt;
      xt.x = 3.0f * (acc2[0][j] - acc1[0][j]);
      xt.y = 3.0f * (acc2[1][j] - acc1[1][j]);
      xt.z = 3.0f * (acc2[2][j] - acc1[2][j]);
      xt.w = 3.0f * (acc2[3][j] - acc1[3][j]);
      *(float4*)(o + (size_t)(c0 + 8 * tx + j) * NN + r0 + 4 * ty) = xt;
    }
  }
}

// Pass 2: one wave per row, no LDS. Per lane: register-resident sorted top-24
// of u64 keys (tv_bits<<32)|(0xFFFF-idx) — key order IS top_k order (value
// desc, index asc), so comparison order is irrelevant. Plateau fast-path:
// x >= kClamp -> tv == tanh_xla(8) exactly (clamp), skips poly+div.
// Branch-free unrolled insert keeps everything in VGPRs (static indices).
__global__ __launch_bounds__(256) void topk_kernel(float* __restrict__ out) {
  const int t = threadIdx.x;
  const int w = t >> 6;
  const int lane = t & 63;
  const int row = blockIdx.x * 4 + w;     // 0..18431 (layer*NN + row)
  float* rp = out + (size_t)row * NN;
  const float Rclamp = tanh_xla(8.0f);    // exact plateau value
  const unsigned RclampBits = __float_as_uint(Rclamp);

  unsigned long long s[KK];               // ascending; s[0] weakest
#pragma unroll
  for (int q = 0; q < KK; ++q) s[q] = 0ull;

  // Scan: lane owns dwords (s*64+lane)*4 .. +3 (coalesced float4).
  for (int sb = 0; sb < 24; ++sb) {
    float4 x4 = *(const float4*)(rp + (size_t)(sb * 64 + lane) * 4);
    const float* xp = (const float*)&x4;
#pragma unroll
    for (int jj = 0; jj < 4; ++jj) {
      float x = xp[jj];
      if (x > 0.0f) {
        unsigned tvb = (x >= KCLAMP) ? RclampBits
                                     : __float_as_uint(tanh_xla(x));
        unsigned idx16 = (unsigned)(sb * 256 + lane * 4 + jj);
        unsigned long long key =
            ((unsigned long long)tvb << 32) | (0xFFFFu - idx16);
        if (key > s[0]) {
          // Branch-free sorted insert (drop s[0], place key).
#pragma unroll
          for (int i = 0; i < KK - 1; ++i)
            s[i] = (s[i + 1] < key) ? s[i + 1] : ((s[i] < key) ? key : s[i]);
          s[KK - 1] = (s[KK - 1] < key) ? key : s[KK - 1];
        }
      }
    }
  }

  // Merge across the wave: 24 extraction rounds, all-register.
  float resv[KK];
  int resi[KK];
#pragma unroll
  for (int r = 0; r < KK; ++r) { resv[r] = 0.0f; resi[r] = 0; }
#pragma unroll
  for (int r = 0; r < KK; ++r) {
    unsigned long long my = s[KK - 1];
    unsigned long long win = my;
#pragma unroll
    for (int d = 1; d < 64; d <<= 1) {
      unsigned long long o2 = shfl_xor_u64(win, d);
      win = (o2 > win) ? o2 : win;
    }
    if (win == 0ull) break;   // wave-uniform: row exhausted
    resv[r] = __uint_as_float((unsigned)(win >> 32));
    resi[r] = (int)(0xFFFFu - (unsigned)(win & 0xFFFFFFFFull));
    // Pop: unique winner (keys contain unique indices) shifts its list up.
    bool won = (my == win);
#pragma unroll
    for (int i = KK - 1; i > 0; --i) s[i] = won ? s[i - 1] : s[i];
    s[0] = won ? 0ull : s[0];
  }

  // Zero the row (lane-owned float4s), then owner-lane scatter: same-thread
  // same-address ordering guarantees the scatter survives.
  float4 z = make_float4(0.f, 0.f, 0.f, 0.f);
  for (int sb = 0; sb < 24; ++sb)
    *(float4*)(rp + (size_t)(sb * 64 + lane) * 4) = z;
#pragma unroll
  for (int r = 0; r < KK; ++r) {
    float v = resv[r];
    int ix = resi[r];
    if (v > 0.0f && ((ix >> 2) & 63) == lane) rp[ix] = v;
  }
}

extern "C" void kernel_launch(void* const* d_in, const int* in_sizes, int n_in,
                              void* d_out, int out_size, void* d_ws, size_t ws_size,
                              hipStream_t stream) {
  const int*   idx       = (const int*)d_in[0];
  const float* scale_set = (const float*)d_in[2];
  const float* emb1      = (const float*)d_in[3];
  const float* emb2      = (const float*)d_in[4];
  const float* W1        = (const float*)d_in[5];
  const float* b1        = (const float*)d_in[6];
  const float* W2        = (const float*)d_in[7];
  const float* b2        = (const float*)d_in[8];
  float* out = (float*)d_out;

  const size_t VS = (size_t)NL * NN * DD;
  float* vt1 = (float*)d_ws;      // k-major [3][64][6144]
  float* vt2 = vt1 + VS;

  mlp_kernel<<<NN / MB, 256, 0, stream>>>(idx, scale_set, emb1, emb2, W1, b1, W2, b2,
                                          vt1, vt2);
  xmat_kernel<<<dim3(NN / BT, NN / BT, NL), 128, 0, stream>>>(vt1, vt2, out);
  topk_kernel<<<(NL * NN) / 4, 256, 0, stream>>>(out);
}

// Round 9
// 736.263 us; speedup vs baseline: 10.8743x; 1.1320x over previous
//
#include <hip/hip_runtime.h>
#include <hip/hip_bf16.h>

#define NN 6144
#define DD 64
#define NL 3
#define KK 24
#define BT 64   // pair-tile dimension (xmat kernel)
#define KH 32   // k-half staged at a time
#define MB 4    // rows per block (mlp kernel)
#define KCLAMP 7.99881172180175781f
#define BANDLO 6.5f   // tanh(6.5)+1e-6 < Rclamp-1e-6: below this tv<Rclamp provably

typedef unsigned long long ull;

// Bit-level emulation of XLA CPU f32 tanh, FMA variant. Verified bit-exact
// vs reference (rounds 2-8, absmax 0.0).
__device__ __forceinline__ float tanh_xla(float x) {
  float xc = fminf(fmaxf(x, -KCLAMP), KCLAMP);
  float x2 = xc * xc;
  float p = -2.76076847742355e-16f;
  p = fmaf(p, x2, 2.00018790482477e-13f);
  p = fmaf(p, x2, -8.60467152213735e-11f);
  p = fmaf(p, x2, 5.12229709037114e-08f);
  p = fmaf(p, x2, 1.48572235717979e-05f);
  p = fmaf(p, x2, 6.37261928875436e-04f);
  p = fmaf(p, x2, 4.89352455891786e-03f);
  p = xc * p;
  float q = 1.19825839466702e-06f;
  q = fmaf(q, x2, 1.18534705686654e-04f);
  q = fmaf(q, x2, 2.26843463243900e-03f);
  q = fmaf(q, x2, 4.89352518554385e-03f);
  float r = p / q;
  return (fabsf(x) < 0.0004f) ? x : r;
}

__device__ __forceinline__ ull shfl_xor_u64(ull v, int m) {
  unsigned lo = __shfl_xor((unsigned)v, m);
  unsigned hi = __shfl_xor((unsigned)(v >> 32), m);
  return ((ull)hi << 32) | lo;
}

// Kernel A: 3-layer tanh MLP chains, thread = (row, output j). Identical fmaf
// chain order to rounds 2-8 (bit-matches Eigen). Emits k-major vT only.
__global__ __launch_bounds__(256) void mlp_kernel(
    const int* __restrict__ idx, const float* __restrict__ scale_set,
    const float* __restrict__ emb1, const float* __restrict__ emb2,
    const float* __restrict__ W1, const float* __restrict__ b1,
    const float* __restrict__ W2, const float* __restrict__ b2,
    float* __restrict__ vt1, float* __restrict__ vt2) {
  __shared__ float Wt1[DD][DD];                  // W[l][j][k] -> [k][j]
  __shared__ float Wt2[DD][DD];
  __shared__ float bsh1[DD], bsh2[DD];
  __shared__ __align__(16) float o1sh[MB][DD];
  __shared__ __align__(16) float o2sh[MB][DD];
  const int t = threadIdx.x;
  const int r = t >> 6;
  const int j = t & 63;
  const int grow = blockIdx.x * MB + r;

  {
    int g = idx[grow];
    if (j < 16) {
      ((float4*)&o1sh[r][0])[j] = ((const float4*)(emb1 + (size_t)g * DD))[j];
      ((float4*)&o2sh[r][0])[j] = ((const float4*)(emb2 + (size_t)g * DD))[j];
    }
  }

  for (int l = 0; l < NL; ++l) {
    __syncthreads();
    {
      const float* w1p = W1 + ((size_t)l * DD + j) * DD + r * 16;
      const float* w2p = W2 + ((size_t)l * DD + j) * DD + r * 16;
#pragma unroll
      for (int w = 0; w < 4; ++w) {
        float4 a = *(const float4*)(w1p + 4 * w);
        float4 b = *(const float4*)(w2p + 4 * w);
        int k0 = r * 16 + 4 * w;
        Wt1[k0 + 0][j] = a.x; Wt1[k0 + 1][j] = a.y;
        Wt1[k0 + 2][j] = a.z; Wt1[k0 + 3][j] = a.w;
        Wt2[k0 + 0][j] = b.x; Wt2[k0 + 1][j] = b.y;
        Wt2[k0 + 2][j] = b.z; Wt2[k0 + 3][j] = b.w;
      }
    }
    if (t < DD) { bsh1[t] = b1[l * DD + t]; bsh2[t] = b2[l * DD + t]; }
    __syncthreads();

    const float s = scale_set[l];
    float a1 = 0.0f, a2 = 0.0f;
#pragma unroll
    for (int kb = 0; kb < 16; ++kb) {
      float4 s1 = ((const float4*)&o1sh[r][0])[kb];
      float4 s2 = ((const float4*)&o2sh[r][0])[kb];
      int k0 = 4 * kb;
      a1 = fmaf(s1.x * s, Wt1[k0 + 0][j], a1);
      a1 = fmaf(s1.y * s, Wt1[k0 + 1][j], a1);
      a1 = fmaf(s1.z * s, Wt1[k0 + 2][j], a1);
      a1 = fmaf(s1.w * s, Wt1[k0 + 3][j], a1);
      a2 = fmaf(s2.x * s, Wt2[k0 + 0][j], a2);
      a2 = fmaf(s2.y * s, Wt2[k0 + 1][j], a2);
      a2 = fmaf(s2.z * s, Wt2[k0 + 2][j], a2);
      a2 = fmaf(s2.w * s, Wt2[k0 + 3][j], a2);
    }
    float t1 = tanh_xla(3.0f * (a1 + bsh1[j]));
    float t2 = tanh_xla(3.0f * (a2 + bsh2[j]));
    __syncthreads();
    o1sh[r][j] = t1;
    o2sh[r][j] = t2;
    vt1[((size_t)l * DD + j) * NN + grow] = t1;
    vt2[((size_t)l * DD + j) * NN + grow] = t2;
  }
}

// Pass 1: antisymmetric pair-tile GEMM (unchanged from round 7/8; bit-exact
// mirror store via IEEE-mul commutativity).
__global__ __launch_bounds__(128) void xmat_kernel(
    const float* __restrict__ vt1, const float* __restrict__ vt2,
    float* __restrict__ out) {
  __shared__ float R1h[KH][BT];
  __shared__ float R2h[KH][BT];
  __shared__ float C1h[KH][BT];
  __shared__ float C2h[KH][BT];

  const int a = blockIdx.x;
  const int b = blockIdx.y;
  if (b < a) return;
  const int l = blockIdx.z;
  const int t = threadIdx.x;
  const int r0 = a * BT;
  const int c0 = b * BT;
  const float* w1 = vt1 + (size_t)l * DD * NN;
  const float* w2 = vt2 + (size_t)l * DD * NN;
  float* o = out + (size_t)l * NN * NN;

  const int ty = t >> 3;
  const int tx = t & 7;
  const int stk = t >> 4;
  const int stc = (t & 15) * 4;

  float acc1[4][8] = {{0.f}}, acc2[4][8] = {{0.f}};

#pragma unroll
  for (int h = 0; h < 2; ++h) {
    __syncthreads();
#pragma unroll
    for (int m = 0; m < 4; ++m) {
      int k = m * 8 + stk;
      const size_t src = (size_t)(h * KH + k) * NN;
      *(float4*)&R1h[k][stc] = *(const float4*)(w1 + src + r0 + stc);
      *(float4*)&R2h[k][stc] = *(const float4*)(w2 + src + r0 + stc);
      *(float4*)&C1h[k][stc] = *(const float4*)(w1 + src + c0 + stc);
      *(float4*)&C2h[k][stc] = *(const float4*)(w2 + src + c0 + stc);
    }
    __syncthreads();
#pragma unroll 4
    for (int kk = 0; kk < KH; ++kk) {
      float4 rv1 = *(const float4*)&R1h[kk][4 * ty];
      float4 rv2 = *(const float4*)&R2h[kk][4 * ty];
      float4 cv1a = *(const float4*)&C1h[kk][8 * tx];
      float4 cv1b = *(const float4*)&C1h[kk][8 * tx + 4];
      float4 cv2a = *(const float4*)&C2h[kk][8 * tx];
      float4 cv2b = *(const float4*)&C2h[kk][8 * tx + 4];
      const float* r1 = (const float*)&rv1;
      const float* r2 = (const float*)&rv2;
      float c1[8], c2[8];
      *(float4*)&c1[0] = cv1a; *(float4*)&c1[4] = cv1b;
      *(float4*)&c2[0] = cv2a; *(float4*)&c2[4] = cv2b;
#pragma unroll
      for (int i = 0; i < 4; ++i)
#pragma unroll
        for (int j = 0; j < 8; ++j) {
          acc1[i][j] = fmaf(r1[i], c2[j], acc1[i][j]);
          acc2[i][j] = fmaf(r2[i], c1[j], acc2[i][j]);
        }
    }
  }

#pragma unroll
  for (int i = 0; i < 4; ++i) {
    float4 xa, xb;
    xa.x = 3.0f * (acc1[i][0] - acc2[i][0]);
    xa.y = 3.0f * (acc1[i][1] - acc2[i][1]);
    xa.z = 3.0f * (acc1[i][2] - acc2[i][2]);
    xa.w = 3.0f * (acc1[i][3] - acc2[i][3]);
    xb.x = 3.0f * (acc1[i][4] - acc2[i][4]);
    xb.y = 3.0f * (acc1[i][5] - acc2[i][5]);
    xb.z = 3.0f * (acc1[i][6] - acc2[i][6]);
    xb.w = 3.0f * (acc1[i][7] - acc2[i][7]);
    float* p = o + (size_t)(r0 + 4 * ty + i) * NN + c0 + 8 * tx;
    *(float4*)p = xa;
    *(float4*)(p + 4) = xb;
  }
  if (b > a) {
#pragma unroll
    for (int j = 0; j < 8; ++j) {
      float4 xt;
      xt.x = 3.0f * (acc2[0][j] - acc1[0][j]);
      xt.y = 3.0f * (acc2[1][j] - acc1[1][j]);
      xt.z = 3.0f * (acc2[2][j] - acc1[2][j]);
      xt.w = 3.0f * (acc2[3][j] - acc1[3][j]);
      *(float4*)(o + (size_t)(c0 + 8 * tx + j) * NN + r0 + 4 * ty) = xt;
    }
  }
}

// Pass 2: one wave per row. Ascending-index scan with EXACT plateau freeze:
// once >=24 entries with tv==Rclamp have been seen (ballot-counted), any later
// entry with tv<=Rclamp provably loses -> only the band x in (6.5,clamp) gets
// full tanh; plateau positions recorded in per-lane 96-bit register masks.
// Keys = KOFF|(tv_bits<<32)|(0xFFFF-idx) (= top_k order: value desc, idx asc),
// KOFF=2^62 keeps every key a positive normal f64 -> v_min/max_f64 insert
// (2 insts/slot). Extraction: 24 rounds merging plateau stream (ffs+butterfly)
// with per-lane key lists; lane r keeps winner r (no result arrays).
__global__ __launch_bounds__(256, 4) void topk_kernel(float* __restrict__ out) {
  const int t = threadIdx.x;
  const int w = t >> 6;
  const int lane = t & 63;
  const int row = blockIdx.x * 4 + w;     // layer*NN + row
  float* rp = out + (size_t)row * NN;
  const float Rclamp = tanh_xla(8.0f);    // exact plateau value (clamp)
  const unsigned RB = __float_as_uint(Rclamp);
  const ull KOFF = 1ull << 62;
  const ull RKEYHI = (ull)RB << 32;
  const double EMPTYD = __longlong_as_double((long long)KOFF);

  ull mlo = 0ull, mhi = 0ull;   // plateau slot masks (slots 0-63, 64-95)
  double s[KK];                 // key list (ascending), f64 bit patterns
#pragma unroll
  for (int q = 0; q < KK; ++q) s[q] = EMPTYD;
  ull s0k = KOFF;               // cached weakest key (u64 view)
  unsigned plat_total = 0;      // wave-uniform plateau count

  float4 cur = *(const float4*)(rp + (size_t)lane * 4);
  for (int sb = 0; sb < 24; ++sb) {
    float4 nxt = cur;
    if (sb < 23) nxt = *(const float4*)(rp + (size_t)((sb + 1) * 64 + lane) * 4);
    const float* xp = (const float*)&cur;
    const unsigned gbase = (unsigned)(sb * 256 + lane * 4);

    bool p0 = cur.x >= KCLAMP, p1 = cur.y >= KCLAMP,
         p2 = cur.z >= KCLAMP, p3 = cur.w >= KCLAMP;
    unsigned nib = (p0 ? 1u : 0u) | (p1 ? 2u : 0u) | (p2 ? 4u : 0u) | (p3 ? 8u : 0u);

    if (plat_total < 24) {
      // FULL mode: every positive sub-clamp entry gets exact tanh + insert.
      plat_total += (unsigned)__popcll(__ballot(p0));
      plat_total += (unsigned)__popcll(__ballot(p1));
      plat_total += (unsigned)__popcll(__ballot(p2));
      plat_total += (unsigned)__popcll(__ballot(p3));
#pragma unroll
      for (int jj = 0; jj < 4; ++jj) {
        float x = xp[jj];
        if (x > 0.0f && x < KCLAMP) {
          float tv = tanh_xla(x);
          ull key = KOFF | ((ull)__float_as_uint(tv) << 32) |
                    (ull)(0xFFFFu - (gbase + jj));
          if (key > s0k) {
            double kd = __longlong_as_double((long long)key);
#pragma unroll
            for (int i = 0; i < KK - 1; ++i)
              s[i] = fmin(s[i + 1], fmax(s[i], kd));
            s[KK - 1] = fmax(s[KK - 1], kd);
            s0k = (ull)__double_as_longlong(s[0]);
          }
        }
      }
    } else {
      // SPARSE mode: >=24 lower-index entries with tv==Rclamp exist, so only
      // the band (BANDLO, KCLAMP) can still rank (tv >= Rclamp possible).
      bool b0 = (cur.x > BANDLO) & !p0, b1 = (cur.y > BANDLO) & !p1,
           b2 = (cur.z > BANDLO) & !p2, b3 = (cur.w > BANDLO) & !p3;
      if (__any(b0 | b1 | b2 | b3)) {
#pragma unroll
        for (int jj = 0; jj < 4; ++jj) {
          bool bj = (jj == 0) ? b0 : (jj == 1) ? b1 : (jj == 2) ? b2 : b3;
          if (bj) {
            float tv = tanh_xla(xp[jj]);
            unsigned tvb = __float_as_uint(tv);
            if (tvb > RB) {
              ull key = KOFF | ((ull)tvb << 32) | (ull)(0xFFFFu - (gbase + jj));
              if (key > s0k) {
                double kd = __longlong_as_double((long long)key);
#pragma unroll
                for (int i = 0; i < KK - 1; ++i)
                  s[i] = fmin(s[i + 1], fmax(s[i], kd));
                s[KK - 1] = fmax(s[KK - 1], kd);
                s0k = (ull)__double_as_longlong(s[0]);
              }
            } else if (tvb == RB) {
              nib |= 1u << jj;   // joins the index-ordered plateau stream
            }
          }
        }
      }
    }
    // Fold plateau nibble into the 96-bit mask (uniform shift amounts).
    if (sb < 16) mlo |= ((ull)nib) << (sb * 4);
    else         mhi |= ((ull)nib) << ((sb - 16) * 4);
    cur = nxt;
  }

  // Extraction: 24 rounds; winner r parked in lane r's (wv,wi).
  float wv = 0.0f;
  int wi = 0;
  for (int r = 0; r < KK; ++r) {
    ull pk = KOFF;
    if (mlo | mhi) {
      int e = mlo ? __builtin_ctzll(mlo) : (64 + __builtin_ctzll(mhi));
      int pidx = ((e >> 2) << 8) + lane * 4 + (e & 3);
      pk = KOFF | RKEYHI | (ull)(0xFFFFu - (unsigned)pidx);
    }
    ull lk = (ull)__double_as_longlong(s[KK - 1]);
    bool fromList = lk > pk;
    ull cand = fromList ? lk : pk;
    ull win = cand;
#pragma unroll
    for (int d = 1; d < 64; d <<= 1) {
      ull o2 = shfl_xor_u64(win, d);
      win = (o2 > win) ? o2 : win;
    }
    if (win == KOFF) break;   // wave-uniform: row exhausted
    if (lane == r) {
      wv = __uint_as_float((unsigned)((win >> 32) & 0x3FFFFFFFu));
      wi = 0xFFFF - (int)(win & 0xFFFFull);
    }
    if (cand == win) {        // unique winner (indices unique)
      if (fromList) {
#pragma unroll
        for (int i = KK - 1; i > 0; --i) s[i] = s[i - 1];
        s[0] = EMPTYD;
      } else {
        if (mlo) mlo &= mlo - 1;
        else     mhi &= mhi - 1;
      }
    }
  }

  // Zero the row, drain stores, then scatter winners (lanes 0-23).
  float4 z = make_float4(0.f, 0.f, 0.f, 0.f);
  for (int sb = 0; sb < 24; ++sb)
    *(float4*)(rp + (size_t)(sb * 64 + lane) * 4) = z;
  asm volatile("s_waitcnt vmcnt(0)" ::: "memory");
  if (wv > 0.0f) rp[wi] = wv;
}

extern "C" void kernel_launch(void* const* d_in, const int* in_sizes, int n_in,
                              void* d_out, int out_size, void* d_ws, size_t ws_size,
                              hipStream_t stream) {
  const int*   idx       = (const int*)d_in[0];
  const float* scale_set = (const float*)d_in[2];
  const float* emb1      = (const float*)d_in[3];
  const float* emb2      = (const float*)d_in[4];
  const float* W1        = (const float*)d_in[5];
  const float* b1        = (const float*)d_in[6];
  const float* W2        = (const float*)d_in[7];
  const float* b2        = (const float*)d_in[8];
  float* out = (float*)d_out;

  const size_t VS = (size_t)NL * NN * DD;
  float* vt1 = (float*)d_ws;      // k-major [3][64][6144]
  float* vt2 = vt1 + VS;

  mlp_kernel<<<NN / MB, 256, 0, stream>>>(idx, scale_set, emb1, emb2, W1, b1, W2, b2,
                                          vt1, vt2);
  xmat_kernel<<<dim3(NN / BT, NN / BT, NL), 128, 0, stream>>>(vt1, vt2, out);
  topk_kernel<<<(NL * NN) / 4, 256, 0, stream>>>(out);
}

// Round 11
// 658.065 us; speedup vs baseline: 12.1665x; 1.1188x over previous
//
#include <hip/hip_runtime.h>
#include <hip/hip_bf16.h>

#define NN 6144
#define DD 64
#define NL 3
#define KK 24
#define BT 64   // pair-tile dimension (xmat kernel)
#define KH 32   // k-half staged at a time
#define MB 4    // rows per block (mlp kernel)
#define KCLAMP 7.99881172180175781f
#define BANDLO 6.5f   // tanh(6.5)+1e-6 < Rclamp-1e-6: below this tv<RB provably

typedef unsigned long long ull;

// Bit-level emulation of XLA CPU f32 tanh, FMA variant. Verified bit-exact
// vs reference (rounds 2-9, absmax 0.0).
__device__ __forceinline__ float tanh_xla(float x) {
  float xc = fminf(fmaxf(x, -KCLAMP), KCLAMP);
  float x2 = xc * xc;
  float p = -2.76076847742355e-16f;
  p = fmaf(p, x2, 2.00018790482477e-13f);
  p = fmaf(p, x2, -8.60467152213735e-11f);
  p = fmaf(p, x2, 5.12229709037114e-08f);
  p = fmaf(p, x2, 1.48572235717979e-05f);
  p = fmaf(p, x2, 6.37261928875436e-04f);
  p = fmaf(p, x2, 4.89352455891786e-03f);
  p = xc * p;
  float q = 1.19825839466702e-06f;
  q = fmaf(q, x2, 1.18534705686654e-04f);
  q = fmaf(q, x2, 2.26843463243900e-03f);
  q = fmaf(q, x2, 4.89352518554385e-03f);
  float r = p / q;
  return (fabsf(x) < 0.0004f) ? x : r;
}

__device__ __forceinline__ ull shfl_xor_u64(ull v, int m) {
  unsigned lo = __shfl_xor((unsigned)v, m);
  unsigned hi = __shfl_xor((unsigned)(v >> 32), m);
  return ((ull)hi << 32) | lo;
}

// Kernel A: 3-layer tanh MLP chains (unchanged; bit-matches Eigen).
__global__ __launch_bounds__(256) void mlp_kernel(
    const int* __restrict__ idx, const float* __restrict__ scale_set,
    const float* __restrict__ emb1, const float* __restrict__ emb2,
    const float* __restrict__ W1, const float* __restrict__ b1,
    const float* __restrict__ W2, const float* __restrict__ b2,
    float* __restrict__ vt1, float* __restrict__ vt2) {
  __shared__ float Wt1[DD][DD];
  __shared__ float Wt2[DD][DD];
  __shared__ float bsh1[DD], bsh2[DD];
  __shared__ __align__(16) float o1sh[MB][DD];
  __shared__ __align__(16) float o2sh[MB][DD];
  const int t = threadIdx.x;
  const int r = t >> 6;
  const int j = t & 63;
  const int grow = blockIdx.x * MB + r;

  {
    int g = idx[grow];
    if (j < 16) {
      ((float4*)&o1sh[r][0])[j] = ((const float4*)(emb1 + (size_t)g * DD))[j];
      ((float4*)&o2sh[r][0])[j] = ((const float4*)(emb2 + (size_t)g * DD))[j];
    }
  }

  for (int l = 0; l < NL; ++l) {
    __syncthreads();
    {
      const float* w1p = W1 + ((size_t)l * DD + j) * DD + r * 16;
      const float* w2p = W2 + ((size_t)l * DD + j) * DD + r * 16;
#pragma unroll
      for (int w = 0; w < 4; ++w) {
        float4 a = *(const float4*)(w1p + 4 * w);
        float4 b = *(const float4*)(w2p + 4 * w);
        int k0 = r * 16 + 4 * w;
        Wt1[k0 + 0][j] = a.x; Wt1[k0 + 1][j] = a.y;
        Wt1[k0 + 2][j] = a.z; Wt1[k0 + 3][j] = a.w;
        Wt2[k0 + 0][j] = b.x; Wt2[k0 + 1][j] = b.y;
        Wt2[k0 + 2][j] = b.z; Wt2[k0 + 3][j] = b.w;
      }
    }
    if (t < DD) { bsh1[t] = b1[l * DD + t]; bsh2[t] = b2[l * DD + t]; }
    __syncthreads();

    const float s = scale_set[l];
    float a1 = 0.0f, a2 = 0.0f;
#pragma unroll
    for (int kb = 0; kb < 16; ++kb) {
      float4 s1 = ((const float4*)&o1sh[r][0])[kb];
      float4 s2 = ((const float4*)&o2sh[r][0])[kb];
      int k0 = 4 * kb;
      a1 = fmaf(s1.x * s, Wt1[k0 + 0][j], a1);
      a1 = fmaf(s1.y * s, Wt1[k0 + 1][j], a1);
      a1 = fmaf(s1.z * s, Wt1[k0 + 2][j], a1);
      a1 = fmaf(s1.w * s, Wt1[k0 + 3][j], a1);
      a2 = fmaf(s2.x * s, Wt2[k0 + 0][j], a2);
      a2 = fmaf(s2.y * s, Wt2[k0 + 1][j], a2);
      a2 = fmaf(s2.z * s, Wt2[k0 + 2][j], a2);
      a2 = fmaf(s2.w * s, Wt2[k0 + 3][j], a2);
    }
    float t1 = tanh_xla(3.0f * (a1 + bsh1[j]));
    float t2 = tanh_xla(3.0f * (a2 + bsh2[j]));
    __syncthreads();
    o1sh[r][j] = t1;
    o2sh[r][j] = t2;
    vt1[((size_t)l * DD + j) * NN + grow] = t1;
    vt2[((size_t)l * DD + j) * NN + grow] = t2;
  }
}

// Pass 1: antisymmetric pair-tile GEMM (unchanged; bit-exact mirror store).
__global__ __launch_bounds__(128) void xmat_kernel(
    const float* __restrict__ vt1, const float* __restrict__ vt2,
    float* __restrict__ out) {
  __shared__ float R1h[KH][BT];
  __shared__ float R2h[KH][BT];
  __shared__ float C1h[KH][BT];
  __shared__ float C2h[KH][BT];

  const int a = blockIdx.x;
  const int b = blockIdx.y;
  if (b < a) return;
  const int l = blockIdx.z;
  const int t = threadIdx.x;
  const int r0 = a * BT;
  const int c0 = b * BT;
  const float* w1 = vt1 + (size_t)l * DD * NN;
  const float* w2 = vt2 + (size_t)l * DD * NN;
  float* o = out + (size_t)l * NN * NN;

  const int ty = t >> 3;
  const int tx = t & 7;
  const int stk = t >> 4;
  const int stc = (t & 15) * 4;

  float acc1[4][8] = {{0.f}}, acc2[4][8] = {{0.f}};

#pragma unroll
  for (int h = 0; h < 2; ++h) {
    __syncthreads();
#pragma unroll
    for (int m = 0; m < 4; ++m) {
      int k = m * 8 + stk;
      const size_t src = (size_t)(h * KH + k) * NN;
      *(float4*)&R1h[k][stc] = *(const float4*)(w1 + src + r0 + stc);
      *(float4*)&R2h[k][stc] = *(const float4*)(w2 + src + r0 + stc);
      *(float4*)&C1h[k][stc] = *(const float4*)(w1 + src + c0 + stc);
      *(float4*)&C2h[k][stc] = *(const float4*)(w2 + src + c0 + stc);
    }
    __syncthreads();
#pragma unroll 4
    for (int kk = 0; kk < KH; ++kk) {
      float4 rv1 = *(const float4*)&R1h[kk][4 * ty];
      float4 rv2 = *(const float4*)&R2h[kk][4 * ty];
      float4 cv1a = *(const float4*)&C1h[kk][8 * tx];
      float4 cv1b = *(const float4*)&C1h[kk][8 * tx + 4];
      float4 cv2a = *(const float4*)&C2h[kk][8 * tx];
      float4 cv2b = *(const float4*)&C2h[kk][8 * tx + 4];
      const float* r1 = (const float*)&rv1;
      const float* r2 = (const float*)&rv2;
      float c1[8], c2[8];
      *(float4*)&c1[0] = cv1a; *(float4*)&c1[4] = cv1b;
      *(float4*)&c2[0] = cv2a; *(float4*)&c2[4] = cv2b;
#pragma unroll
      for (int i = 0; i < 4; ++i)
#pragma unroll
        for (int j = 0; j < 8; ++j) {
          acc1[i][j] = fmaf(r1[i], c2[j], acc1[i][j]);
          acc2[i][j] = fmaf(r2[i], c1[j], acc2[i][j]);
        }
    }
  }

#pragma unroll
  for (int i = 0; i < 4; ++i) {
    float4 xa, xb;
    xa.x = 3.0f * (acc1[i][0] - acc2[i][0]);
    xa.y = 3.0f * (acc1[i][1] - acc2[i][1]);
    xa.z = 3.0f * (acc1[i][2] - acc2[i][2]);
    xa.w = 3.0f * (acc1[i][3] - acc2[i][3]);
    xb.x = 3.0f * (acc1[i][4] - acc2[i][4]);
    xb.y = 3.0f * (acc1[i][5] - acc2[i][5]);
    xb.z = 3.0f * (acc1[i][6] - acc2[i][6]);
    xb.w = 3.0f * (acc1[i][7] - acc2[i][7]);
    float* p = o + (size_t)(r0 + 4 * ty + i) * NN + c0 + 8 * tx;
    *(float4*)p = xa;
    *(float4*)(p + 4) = xb;
  }
  if (b > a) {
#pragma unroll
    for (int j = 0; j < 8; ++j) {
      float4 xt;
      xt.x = 3.0f * (acc2[0][j] - acc1[0][j]);
      xt.y = 3.0f * (acc2[1][j] - acc1[1][j]);
      xt.z = 3.0f * (acc2[2][j] - acc1[2][j]);
      xt.w = 3.0f * (acc2[3][j] - acc1[3][j]);
      *(float4*)(o + (size_t)(c0 + 8 * tx + j) * NN + r0 + 4 * ty) = xt;
    }
  }
}

// Pass 2: one wave per row. FAST PATH: select the first 24 RB-class entries
// (tv bits == RB: plateau x>=clamp, or band (6.5,clamp) classifying ==RB)
// in ASCENDING ELEMENT INDEX order (index = lane*4+jj within a step: rank =
// T + all-RB-in-lower-lanes + own-lane-smaller-jj). All winners have value
// exactly Rclamp. Sound: x<=6.5 => tv<RB provably; tvb>RB sets flag.
// FALLBACK (wave-uniform: T<24 or flag): round-9 machinery (validated).
__global__ __launch_bounds__(256, 2) void topk_kernel(float* __restrict__ out) {
  const int t = threadIdx.x;
  const int w = t >> 6;
  const int lane = t & 63;
  const int row = blockIdx.x * 4 + w;     // layer*NN + row
  float* rp = out + (size_t)row * NN;
  const float Rclamp = tanh_xla(8.0f);    // exact plateau value (clamp)
  const unsigned RB = __float_as_uint(Rclamp);
  const ull lmask = (1ull << lane) - 1;

  ull wlo = 0ull, whi = 0ull;   // winner bit masks (bit e=sb*4+jj)
  unsigned T = 0;               // wave-uniform RB-class count so far
  bool flag = false;            // saw tvb > RB (above-plateau wobble)

  float4 cur = *(const float4*)(rp + (size_t)lane * 4);
  for (int sb = 0; sb < 24; ++sb) {
    float4 nxt = cur;
    if (sb < 23) nxt = *(const float4*)(rp + (size_t)((sb + 1) * 64 + lane) * 4);

    bool p0 = cur.x >= KCLAMP, p1 = cur.y >= KCLAMP,
         p2 = cur.z >= KCLAMP, p3 = cur.w >= KCLAMP;
    unsigned rbnib = (p0 ? 1u : 0u) | (p1 ? 2u : 0u) |
                     (p2 ? 4u : 0u) | (p3 ? 8u : 0u);

    // Band entries need exact tanh to classify ==RB (RB-class) / >RB (flag).
    bool b0 = (cur.x > BANDLO) & !p0, b1 = (cur.y > BANDLO) & !p1,
         b2 = (cur.z > BANDLO) & !p2, b3 = (cur.w > BANDLO) & !p3;
    if (__any(b0 | b1 | b2 | b3)) {
      if (b0) { unsigned v = __float_as_uint(tanh_xla(cur.x));
                if (v == RB) rbnib |= 1u; else if (v > RB) flag = true; }
      if (b1) { unsigned v = __float_as_uint(tanh_xla(cur.y));
                if (v == RB) rbnib |= 2u; else if (v > RB) flag = true; }
      if (b2) { unsigned v = __float_as_uint(tanh_xla(cur.z));
                if (v == RB) rbnib |= 4u; else if (v > RB) flag = true; }
      if (b3) { unsigned v = __float_as_uint(tanh_xla(cur.w));
                if (v == RB) rbnib |= 8u; else if (v > RB) flag = true; }
    }

    if (T < 24u) {
      ull bl0 = __ballot((rbnib & 1u) != 0u);
      ull bl1 = __ballot((rbnib & 2u) != 0u);
      ull bl2 = __ballot((rbnib & 4u) != 0u);
      ull bl3 = __ballot((rbnib & 8u) != 0u);
      // Rank in ascending element index (lane-major, jj-minor):
      // all RB entries in lower lanes + own-lane entries with smaller jj.
      unsigned below = (unsigned)__popcll(bl0 & lmask) +
                       (unsigned)__popcll(bl1 & lmask) +
                       (unsigned)__popcll(bl2 & lmask) +
                       (unsigned)__popcll(bl3 & lmask);
      unsigned base = T + below;
#pragma unroll
      for (int jj = 0; jj < 4; ++jj) {
        if (rbnib & (1u << jj)) {
          unsigned rk = base + (unsigned)__builtin_popcount(rbnib & ((1u << jj) - 1u));
          if (rk < 24u) {
            if (sb < 16) wlo |= 1ull << (sb * 4 + jj);
            else         whi |= 1ull << ((sb - 16) * 4 + jj);
          }
        }
      }
      T += (unsigned)__popcll(bl0) + (unsigned)__popcll(bl1) +
           (unsigned)__popcll(bl2) + (unsigned)__popcll(bl3);
    }
    cur = nxt;
  }

  if (T >= 24u && !__any(flag)) {
    // FAST: zero the row, then scatter winner bits (all value Rclamp; winner
    // addresses are lane-owned -> same-thread ordering after waitcnt).
    float4 z = make_float4(0.f, 0.f, 0.f, 0.f);
    for (int sb = 0; sb < 24; ++sb)
      *(float4*)(rp + (size_t)(sb * 64 + lane) * 4) = z;
    asm volatile("s_waitcnt vmcnt(0)" ::: "memory");
    while (wlo) {
      int e = __builtin_ctzll(wlo);
      rp[(e >> 2) * 256 + lane * 4 + (e & 3)] = Rclamp;
      wlo &= wlo - 1;
    }
    while (whi) {
      int e = __builtin_ctzll(whi);
      rp[(16 + (e >> 2)) * 256 + lane * 4 + (e & 3)] = Rclamp;
      whi &= whi - 1;
    }
    return;
  }

  // FALLBACK: round-9 full-list scan + merge extraction (exact, validated).
  {
    const ull KOFF = 1ull << 62;
    const ull RKEYHI = (ull)RB << 32;
    const double EMPTYD = __longlong_as_double((long long)KOFF);
    ull mlo = 0ull, mhi = 0ull;   // plateau (x>=clamp) slot masks
    double s[KK];
#pragma unroll
    for (int q = 0; q < KK; ++q) s[q] = EMPTYD;
    ull s0k = KOFF;

    for (int sb = 0; sb < 24; ++sb) {
      float4 x4 = *(const float4*)(rp + (size_t)(sb * 64 + lane) * 4);
      const float* xp = (const float*)&x4;
      const unsigned gbase = (unsigned)(sb * 256 + lane * 4);
      unsigned nib = 0u;
#pragma unroll
      for (int jj = 0; jj < 4; ++jj) {
        float x = xp[jj];
        if (x >= KCLAMP) {
          nib |= 1u << jj;
        } else if (x > 0.0f) {
          float tv = tanh_xla(x);
          ull key = KOFF | ((ull)__float_as_uint(tv) << 32) |
                    (ull)(0xFFFFu - (gbase + jj));
          if (key > s0k) {
            double kd = __longlong_as_double((long long)key);
#pragma unroll
            for (int i = 0; i < KK - 1; ++i)
              s[i] = fmin(s[i + 1], fmax(s[i], kd));
            s[KK - 1] = fmax(s[KK - 1], kd);
            s0k = (ull)__double_as_longlong(s[0]);
          }
        }
      }
      if (sb < 16) mlo |= ((ull)nib) << (sb * 4);
      else         mhi |= ((ull)nib) << ((sb - 16) * 4);
    }

    float wv = 0.0f;
    int wi = 0;
    for (int r = 0; r < KK; ++r) {
      ull pk = KOFF;
      if (mlo | mhi) {
        int e = mlo ? __builtin_ctzll(mlo) : (64 + __builtin_ctzll(mhi));
        int pidx = ((e >> 2) << 8) + lane * 4 + (e & 3);
        pk = KOFF | RKEYHI | (ull)(0xFFFFu - (unsigned)pidx);
      }
      ull lk = (ull)__double_as_longlong(s[KK - 1]);
      bool fromList = lk > pk;
      ull cand = fromList ? lk : pk;
      ull win = cand;
#pragma unroll
      for (int d = 1; d < 64; d <<= 1) {
        ull o2 = shfl_xor_u64(win, d);
        win = (o2 > win) ? o2 : win;
      }
      if (win == KOFF) break;
      if (lane == r) {
        wv = __uint_as_float((unsigned)((win >> 32) & 0x3FFFFFFFu));
        wi = 0xFFFF - (int)(win & 0xFFFFull);
      }
      if (cand == win) {
        if (fromList) {
#pragma unroll
          for (int i = KK - 1; i > 0; --i) s[i] = s[i - 1];
          s[0] = EMPTYD;
        } else {
          if (mlo) mlo &= mlo - 1;
          else     mhi &= mhi - 1;
        }
      }
    }

    float4 z = make_float4(0.f, 0.f, 0.f, 0.f);
    for (int sb = 0; sb < 24; ++sb)
      *(float4*)(rp + (size_t)(sb * 64 + lane) * 4) = z;
    asm volatile("s_waitcnt vmcnt(0)" ::: "memory");
    if (wv > 0.0f) rp[wi] = wv;
  }
}

extern "C" void kernel_launch(void* const* d_in, const int* in_sizes, int n_in,
                              void* d_out, int out_size, void* d_ws, size_t ws_size,
                              hipStream_t stream) {
  const int*   idx       = (const int*)d_in[0];
  const float* scale_set = (const float*)d_in[2];
  const float* emb1      = (const float*)d_in[3];
  const float* emb2      = (const float*)d_in[4];
  const float* W1        = (const float*)d_in[5];
  const float* b1        = (const float*)d_in[6];
  const float* W2        = (const float*)d_in[7];
  const float* b2        = (const float*)d_in[8];
  float* out = (float*)d_out;

  const size_t VS = (size_t)NL * NN * DD;
  float* vt1 = (float*)d_ws;      // k-major [3][64][6144]
  float* vt2 = vt1 + VS;

  mlp_kernel<<<NN / MB, 256, 0, stream>>>(idx, scale_set, emb1, emb2, W1, b1, W2, b2,
                                          vt1, vt2);
  xmat_kernel<<<dim3(NN / BT, NN / BT, NL), 128, 0, stream>>>(vt1, vt2, out);
  topk_kernel<<<(NL * NN) / 4, 256, 0, stream>>>(out);
}

// Round 12
// 648.530 us; speedup vs baseline: 12.3454x; 1.0147x over previous
//
#include <hip/hip_runtime.h>
#include <hip/hip_bf16.h>

#define NN 6144
#define DD 64
#define NL 3
#define KK 24
#define BT2 128  // pair-tile dimension (xmat kernel)
#define KH2 16   // k-quarter staged at a time
#define MB 4     // rows per block (mlp kernel)
#define KCLAMP 7.99881172180175781f
#define BANDLO 6.5f   // tanh(6.5)+1e-6 < Rclamp-1e-6: below this tv<RB provably

typedef unsigned long long ull;

// Bit-level emulation of XLA CPU f32 tanh, FMA variant. Verified bit-exact
// vs reference (rounds 2-11, absmax 0.0).
__device__ __forceinline__ float tanh_xla(float x) {
  float xc = fminf(fmaxf(x, -KCLAMP), KCLAMP);
  float x2 = xc * xc;
  float p = -2.76076847742355e-16f;
  p = fmaf(p, x2, 2.00018790482477e-13f);
  p = fmaf(p, x2, -8.60467152213735e-11f);
  p = fmaf(p, x2, 5.12229709037114e-08f);
  p = fmaf(p, x2, 1.48572235717979e-05f);
  p = fmaf(p, x2, 6.37261928875436e-04f);
  p = fmaf(p, x2, 4.89352455891786e-03f);
  p = xc * p;
  float q = 1.19825839466702e-06f;
  q = fmaf(q, x2, 1.18534705686654e-04f);
  q = fmaf(q, x2, 2.26843463243900e-03f);
  q = fmaf(q, x2, 4.89352518554385e-03f);
  float r = p / q;
  return (fabsf(x) < 0.0004f) ? x : r;
}

__device__ __forceinline__ ull shfl_xor_u64(ull v, int m) {
  unsigned lo = __shfl_xor((unsigned)v, m);
  unsigned hi = __shfl_xor((unsigned)(v >> 32), m);
  return ((ull)hi << 32) | lo;
}

// Kernel A: 3-layer tanh MLP chains (unchanged; bit-matches Eigen).
__global__ __launch_bounds__(256) void mlp_kernel(
    const int* __restrict__ idx, const float* __restrict__ scale_set,
    const float* __restrict__ emb1, const float* __restrict__ emb2,
    const float* __restrict__ W1, const float* __restrict__ b1,
    const float* __restrict__ W2, const float* __restrict__ b2,
    float* __restrict__ vt1, float* __restrict__ vt2) {
  __shared__ float Wt1[DD][DD];
  __shared__ float Wt2[DD][DD];
  __shared__ float bsh1[DD], bsh2[DD];
  __shared__ __align__(16) float o1sh[MB][DD];
  __shared__ __align__(16) float o2sh[MB][DD];
  const int t = threadIdx.x;
  const int r = t >> 6;
  const int j = t & 63;
  const int grow = blockIdx.x * MB + r;

  {
    int g = idx[grow];
    if (j < 16) {
      ((float4*)&o1sh[r][0])[j] = ((const float4*)(emb1 + (size_t)g * DD))[j];
      ((float4*)&o2sh[r][0])[j] = ((const float4*)(emb2 + (size_t)g * DD))[j];
    }
  }

  for (int l = 0; l < NL; ++l) {
    __syncthreads();
    {
      const float* w1p = W1 + ((size_t)l * DD + j) * DD + r * 16;
      const float* w2p = W2 + ((size_t)l * DD + j) * DD + r * 16;
#pragma unroll
      for (int w = 0; w < 4; ++w) {
        float4 a = *(const float4*)(w1p + 4 * w);
        float4 b = *(const float4*)(w2p + 4 * w);
        int k0 = r * 16 + 4 * w;
        Wt1[k0 + 0][j] = a.x; Wt1[k0 + 1][j] = a.y;
        Wt1[k0 + 2][j] = a.z; Wt1[k0 + 3][j] = a.w;
        Wt2[k0 + 0][j] = b.x; Wt2[k0 + 1][j] = b.y;
        Wt2[k0 + 2][j] = b.z; Wt2[k0 + 3][j] = b.w;
      }
    }
    if (t < DD) { bsh1[t] = b1[l * DD + t]; bsh2[t] = b2[l * DD + t]; }
    __syncthreads();

    const float s = scale_set[l];
    float a1 = 0.0f, a2 = 0.0f;
#pragma unroll
    for (int kb = 0; kb < 16; ++kb) {
      float4 s1 = ((const float4*)&o1sh[r][0])[kb];
      float4 s2 = ((const float4*)&o2sh[r][0])[kb];
      int k0 = 4 * kb;
      a1 = fmaf(s1.x * s, Wt1[k0 + 0][j], a1);
      a1 = fmaf(s1.y * s, Wt1[k0 + 1][j], a1);
      a1 = fmaf(s1.z * s, Wt1[k0 + 2][j], a1);
      a1 = fmaf(s1.w * s, Wt1[k0 + 3][j], a1);
      a2 = fmaf(s2.x * s, Wt2[k0 + 0][j], a2);
      a2 = fmaf(s2.y * s, Wt2[k0 + 1][j], a2);
      a2 = fmaf(s2.z * s, Wt2[k0 + 2][j], a2);
      a2 = fmaf(s2.w * s, Wt2[k0 + 3][j], a2);
    }
    float t1 = tanh_xla(3.0f * (a1 + bsh1[j]));
    float t2 = tanh_xla(3.0f * (a2 + bsh2[j]));
    __syncthreads();
    o1sh[r][j] = t1;
    o2sh[r][j] = t2;
    vt1[((size_t)l * DD + j) * NN + grow] = t1;
    vt2[((size_t)l * DD + j) * NN + grow] = t2;
  }
}

// Pass 1: antisymmetric pair-tile GEMM, 128x128 tile, 8x8 per-thread register
// tiles (halves DS reads per output vs 4x8; xmat was LDS-pipe-bound). KH2=16
// k-quarters keep LDS at 32KB -> 5 blocks/CU. Chains identical to rounds 7-11
// (sequential k ascending, two separate fmaf chains; mirror bit-exact).
__global__ __launch_bounds__(256) void xmat_kernel(
    const float* __restrict__ vt1, const float* __restrict__ vt2,
    float* __restrict__ out) {
  __shared__ float R1h[KH2][BT2];   // 8KB each -> 32KB total
  __shared__ float R2h[KH2][BT2];
  __shared__ float C1h[KH2][BT2];
  __shared__ float C2h[KH2][BT2];

  const int a = blockIdx.x;
  const int b = blockIdx.y;
  if (b < a) return;
  const int l = blockIdx.z;
  const int t = threadIdx.x;
  const int r0 = a * BT2;
  const int c0 = b * BT2;
  const float* w1 = vt1 + (size_t)l * DD * NN;
  const float* w2 = vt2 + (size_t)l * DD * NN;
  float* o = out + (size_t)l * NN * NN;

  const int ty = t >> 4;          // 0..15 -> rows 8ty..8ty+7
  const int tx = t & 15;          // 0..15 -> cols 8tx..8tx+7
  const int sk = t >> 4;          // staging k 0..15
  const int sq = (t & 15) * 8;    // staging col offset (2 float4s)

  float acc1[8][8] = {{0.f}}, acc2[8][8] = {{0.f}};

#pragma unroll
  for (int h = 0; h < 4; ++h) {
    __syncthreads();   // previous quarter consumed
    {
      const size_t src = (size_t)(h * KH2 + sk) * NN;
      *(float4*)&R1h[sk][sq]     = *(const float4*)(w1 + src + r0 + sq);
      *(float4*)&R1h[sk][sq + 4] = *(const float4*)(w1 + src + r0 + sq + 4);
      *(float4*)&R2h[sk][sq]     = *(const float4*)(w2 + src + r0 + sq);
      *(float4*)&R2h[sk][sq + 4] = *(const float4*)(w2 + src + r0 + sq + 4);
      *(float4*)&C1h[sk][sq]     = *(const float4*)(w1 + src + c0 + sq);
      *(float4*)&C1h[sk][sq + 4] = *(const float4*)(w1 + src + c0 + sq + 4);
      *(float4*)&C2h[sk][sq]     = *(const float4*)(w2 + src + c0 + sq);
      *(float4*)&C2h[sk][sq + 4] = *(const float4*)(w2 + src + c0 + sq + 4);
    }
    __syncthreads();   // quarter ready
#pragma unroll 2
    for (int kk = 0; kk < KH2; ++kk) {
      float r1[8], r2[8], c1[8], c2[8];
      *(float4*)&r1[0] = *(const float4*)&R1h[kk][8 * ty];
      *(float4*)&r1[4] = *(const float4*)&R1h[kk][8 * ty + 4];
      *(float4*)&r2[0] = *(const float4*)&R2h[kk][8 * ty];
      *(float4*)&r2[4] = *(const float4*)&R2h[kk][8 * ty + 4];
      *(float4*)&c1[0] = *(const float4*)&C1h[kk][8 * tx];
      *(float4*)&c1[4] = *(const float4*)&C1h[kk][8 * tx + 4];
      *(float4*)&c2[0] = *(const float4*)&C2h[kk][8 * tx];
      *(float4*)&c2[4] = *(const float4*)&C2h[kk][8 * tx + 4];
#pragma unroll
      for (int i = 0; i < 8; ++i)
#pragma unroll
        for (int j = 0; j < 8; ++j) {
          acc1[i][j] = fmaf(r1[i], c2[j], acc1[i][j]);  // v1_r . v2_c
          acc2[i][j] = fmaf(r2[i], c1[j], acc2[i][j]);  // v2_r . v1_c
        }
    }
  }

  // Direct tile store.
#pragma unroll
  for (int i = 0; i < 8; ++i) {
    float xv[8];
#pragma unroll
    for (int j = 0; j < 8; ++j) xv[j] = 3.0f * (acc1[i][j] - acc2[i][j]);
    float* p = o + (size_t)(r0 + 8 * ty + i) * NN + c0 + 8 * tx;
    *(float4*)p = *(float4*)&xv[0];
    *(float4*)(p + 4) = *(float4*)&xv[4];
  }
  // Mirrored tile store (bit-exact antisymmetric counterpart).
  if (b > a) {
#pragma unroll
    for (int j = 0; j < 8; ++j) {
      float xv[8];
#pragma unroll
      for (int i = 0; i < 8; ++i) xv[i] = 3.0f * (acc2[i][j] - acc1[i][j]);
      float* p = o + (size_t)(c0 + 8 * tx + j) * NN + r0 + 8 * ty;
      *(float4*)p = *(float4*)&xv[0];
      *(float4*)(p + 4) = *(float4*)&xv[4];
    }
  }
}

// Pass 2: one wave per row. Scan classifies only (no ballots): RB-class
// (x>=clamp, or band (6.5,clamp) with tv bits==RB) folds into a 96-bit
// register mask; "supers" (band entries with tv bits > RB: rounding wobble
// above the plateau) stored <=2 per lane as u64 keys. Winners = supers
// (value desc, idx asc) + first (24-S) RB-class by index. Post-scan: early-
// breaking ballot-ranking pass marks RB winners; <=S butterfly rounds extract
// supers. FALLBACK (rare, wave-uniform: lane>2 supers or RB total < 24-S):
// round-9 full-list machinery (validated absmax 0.0).
__global__ __launch_bounds__(256, 2) void topk_kernel(float* __restrict__ out) {
  const int t = threadIdx.x;
  const int w = t >> 6;
  const int lane = t & 63;
  const int row = blockIdx.x * 4 + w;     // layer*NN + row
  float* rp = out + (size_t)row * NN;
  const float Rclamp = tanh_xla(8.0f);    // exact plateau value (clamp)
  const unsigned RB = __float_as_uint(Rclamp);
  const ull KOFF = 1ull << 62;
  const ull lmask = (1ull << lane) - 1;

  ull rblo = 0ull, rbhi = 0ull;   // RB-class bit masks (bit e=sb*4+jj)
  ull sup0 = 0ull, sup1 = 0ull;   // per-lane super keys (<=2)
  int scnt = 0;

  float4 cur = *(const float4*)(rp + (size_t)lane * 4);
  for (int sb = 0; sb < 24; ++sb) {
    float4 nxt = cur;
    if (sb < 23) nxt = *(const float4*)(rp + (size_t)((sb + 1) * 64 + lane) * 4);
    const float* xp = (const float*)&cur;
    const unsigned gbase = (unsigned)(sb * 256 + lane * 4);

    bool p0 = cur.x >= KCLAMP, p1 = cur.y >= KCLAMP,
         p2 = cur.z >= KCLAMP, p3 = cur.w >= KCLAMP;
    unsigned nib = (p0 ? 1u : 0u) | (p1 ? 2u : 0u) |
                   (p2 ? 4u : 0u) | (p3 ? 8u : 0u);

    bool b0 = (cur.x > BANDLO) & !p0, b1 = (cur.y > BANDLO) & !p1,
         b2 = (cur.z > BANDLO) & !p2, b3 = (cur.w > BANDLO) & !p3;
    if (__any(b0 | b1 | b2 | b3)) {
#pragma unroll
      for (int jj = 0; jj < 4; ++jj) {
        bool bj = (jj == 0) ? b0 : (jj == 1) ? b1 : (jj == 2) ? b2 : b3;
        if (bj) {
          unsigned v = __float_as_uint(tanh_xla(xp[jj]));
          if (v == RB) {
            nib |= 1u << jj;
          } else if (v > RB) {
            ull key = KOFF | ((ull)v << 32) | (ull)(0xFFFFu - (gbase + jj));
            if (scnt == 0) sup0 = key;
            else if (scnt == 1) sup1 = key;
            ++scnt;
          }
        }
      }
    }
    if (sb < 16) rblo |= ((ull)nib) << (sb * 4);
    else         rbhi |= ((ull)nib) << ((sb - 16) * 4);
    cur = nxt;
  }

  // Super census (2 ballots; >2 on any lane -> fallback).
  ull bs1 = __ballot(scnt >= 1);
  ull bs2 = __ballot(scnt >= 2);
  bool fb = (__ballot(scnt >= 3) != 0ull);
  unsigned S = (unsigned)__popcll(bs1) + (unsigned)__popcll(bs2);
  unsigned E = (S < 24u) ? S : 24u;
  unsigned C24 = 24u - E;

  // Ranking pass over RB masks (typically breaks after step 0).
  ull klo = 0ull, khi = 0ull;
  if (!fb && C24 > 0u) {
    unsigned cum = 0;
    for (int sb = 0; sb < 24; ++sb) {
      unsigned nib = (unsigned)((sb < 16 ? (rblo >> (sb * 4))
                                         : (rbhi >> ((sb - 16) * 4))) & 15ull);
      ull bl0 = __ballot((nib & 1u) != 0u);
      ull bl1 = __ballot((nib & 2u) != 0u);
      ull bl2 = __ballot((nib & 4u) != 0u);
      ull bl3 = __ballot((nib & 8u) != 0u);
      unsigned below = (unsigned)__popcll(bl0 & lmask) +
                       (unsigned)__popcll(bl1 & lmask) +
                       (unsigned)__popcll(bl2 & lmask) +
                       (unsigned)__popcll(bl3 & lmask);
      unsigned base = cum + below;
#pragma unroll
      for (int jj = 0; jj < 4; ++jj) {
        if (nib & (1u << jj)) {
          unsigned rk = base + (unsigned)__builtin_popcount(nib & ((1u << jj) - 1u));
          if (rk < C24) {
            if (sb < 16) klo |= 1ull << (sb * 4 + jj);
            else         khi |= 1ull << ((sb - 16) * 4 + jj);
          }
        }
      }
      cum += (unsigned)__popcll(bl0) + (unsigned)__popcll(bl1) +
             (unsigned)__popcll(bl2) + (unsigned)__popcll(bl3);
      if (cum >= C24) break;   // wave-uniform; later ranks can't qualify
    }
    if (cum < C24) fb = true;  // not enough RB-class -> sub-RB would matter
  }

  if (!fb) {
    // Extract supers: e-th winner parked in lane e (E <= 24 <= 64 lanes).
    float wv = 0.0f;
    int wi = 0;
    for (unsigned e = 0; e < E; ++e) {
      ull cand = (sup0 > sup1) ? sup0 : sup1;
      ull win = cand;
#pragma unroll
      for (int d = 1; d < 64; d <<= 1) {
        ull o2 = shfl_xor_u64(win, d);
        win = (o2 > win) ? o2 : win;
      }
      if (lane == (int)e) {
        wv = __uint_as_float((unsigned)((win >> 32) & 0x3FFFFFFFu));
        wi = 0xFFFF - (int)(win & 0xFFFFull);
      }
      if (sup0 == win) sup0 = 0ull;
      else if (sup1 == win) sup1 = 0ull;
    }
    // Zero the row, drain, scatter RB winners (Rclamp) + supers (own value).
    float4 z = make_float4(0.f, 0.f, 0.f, 0.f);
    for (int sb = 0; sb < 24; ++sb)
      *(float4*)(rp + (size_t)(sb * 64 + lane) * 4) = z;
    asm volatile("s_waitcnt vmcnt(0)" ::: "memory");
    while (klo) {
      int e = __builtin_ctzll(klo);
      rp[(e >> 2) * 256 + lane * 4 + (e & 3)] = Rclamp;
      klo &= klo - 1;
    }
    while (khi) {
      int e = __builtin_ctzll(khi);
      rp[(16 + (e >> 2)) * 256 + lane * 4 + (e & 3)] = Rclamp;
      khi &= khi - 1;
    }
    if (lane < (int)E && wv > 0.0f) rp[wi] = wv;
    return;
  }

  // FALLBACK: round-9 full-list scan + merge extraction (exact, validated).
  {
    const ull RKEYHI = (ull)RB << 32;
    const double EMPTYD = __longlong_as_double((long long)KOFF);
    ull mlo = 0ull, mhi = 0ull;   // plateau (x>=clamp) slot masks
    double s[KK];
#pragma unroll
    for (int q = 0; q < KK; ++q) s[q] = EMPTYD;
    ull s0k = KOFF;

    for (int sb = 0; sb < 24; ++sb) {
      float4 x4 = *(const float4*)(rp + (size_t)(sb * 64 + lane) * 4);
      const float* xp = (const float*)&x4;
      const unsigned gbase = (unsigned)(sb * 256 + lane * 4);
      unsigned nib = 0u;
#pragma unroll
      for (int jj = 0; jj < 4; ++jj) {
        float x = xp[jj];
        if (x >= KCLAMP) {
          nib |= 1u << jj;
        } else if (x > 0.0f) {
          float tv = tanh_xla(x);
          ull key = KOFF | ((ull)__float_as_uint(tv) << 32) |
                    (ull)(0xFFFFu - (gbase + jj));
          if (key > s0k) {
            double kd = __longlong_as_double((long long)key);
#pragma unroll
            for (int i = 0; i < KK - 1; ++i)
              s[i] = fmin(s[i + 1], fmax(s[i], kd));
            s[KK - 1] = fmax(s[KK - 1], kd);
            s0k = (ull)__double_as_longlong(s[0]);
          }
        }
      }
      if (sb < 16) mlo |= ((ull)nib) << (sb * 4);
      else         mhi |= ((ull)nib) << ((sb - 16) * 4);
    }

    float wv = 0.0f;
    int wi = 0;
    for (int r = 0; r < KK; ++r) {
      ull pk = KOFF;
      if (mlo | mhi) {
        int e = mlo ? __builtin_ctzll(mlo) : (64 + __builtin_ctzll(mhi));
        int pidx = ((e >> 2) << 8) + lane * 4 + (e & 3);
        pk = KOFF | RKEYHI | (ull)(0xFFFFu - (unsigned)pidx);
      }
      ull lk = (ull)__double_as_longlong(s[KK - 1]);
      bool fromList = lk > pk;
      ull cand = fromList ? lk : pk;
      ull win = cand;
#pragma unroll
      for (int d = 1; d < 64; d <<= 1) {
        ull o2 = shfl_xor_u64(win, d);
        win = (o2 > win) ? o2 : win;
      }
      if (win == KOFF) break;
      if (lane == r) {
        wv = __uint_as_float((unsigned)((win >> 32) & 0x3FFFFFFFu));
        wi = 0xFFFF - (int)(win & 0xFFFFull);
      }
      if (cand == win) {
        if (fromList) {
#pragma unroll
          for (int i = KK - 1; i > 0; --i) s[i] = s[i - 1];
          s[0] = EMPTYD;
        } else {
          if (mlo) mlo &= mlo - 1;
          else     mhi &= mhi - 1;
        }
      }
    }

    float4 z = make_float4(0.f, 0.f, 0.f, 0.f);
    for (int sb = 0; sb < 24; ++sb)
      *(float4*)(rp + (size_t)(sb * 64 + lane) * 4) = z;
    asm volatile("s_waitcnt vmcnt(0)" ::: "memory");
    if (wv > 0.0f) rp[wi] = wv;
  }
}

extern "C" void kernel_launch(void* const* d_in, const int* in_sizes, int n_in,
                              void* d_out, int out_size, void* d_ws, size_t ws_size,
                              hipStream_t stream) {
  const int*   idx       = (const int*)d_in[0];
  const float* scale_set = (const float*)d_in[2];
  const float* emb1      = (const float*)d_in[3];
  const float* emb2      = (const float*)d_in[4];
  const float* W1        = (const float*)d_in[5];
  const float* b1        = (const float*)d_in[6];
  const float* W2        = (const float*)d_in[7];
  const float* b2        = (const float*)d_in[8];
  float* out = (float*)d_out;

  const size_t VS = (size_t)NL * NN * DD;
  float* vt1 = (float*)d_ws;      // k-major [3][64][6144]
  float* vt2 = vt1 + VS;

  mlp_kernel<<<NN / MB, 256, 0, stream>>>(idx, scale_set, emb1, emb2, W1, b1, W2, b2,
                                          vt1, vt2);
  xmat_kernel<<<dim3(NN / BT2, NN / BT2, NL), 256, 0, stream>>>(vt1, vt2, out);
  topk_kernel<<<(NL * NN) / 4, 256, 0, stream>>>(out);
}